// Round 9
// baseline (591.293 us; speedup 1.0000x reference)
//
#include <hip/hip_runtime.h>
#include <hip/hip_bf16.h>

typedef __bf16 bf16;
typedef __bf16 bf16x8 __attribute__((ext_vector_type(8)));
typedef __bf16 bf16x4 __attribute__((ext_vector_type(4)));
typedef __bf16 bf16x2 __attribute__((ext_vector_type(2)));
typedef float  f32x4  __attribute__((ext_vector_type(4)));
typedef float  f32x16 __attribute__((ext_vector_type(16)));
typedef unsigned int u32;

#define MFMA(A, B, C)   __builtin_amdgcn_mfma_f32_16x16x32_bf16((A), (B), (C), 0, 0, 0)
#define MFMA32(A, B, C) __builtin_amdgcn_mfma_f32_32x32x16_bf16((A), (B), (C), 0, 0, 0)

static constexpr int BATCH = 4, S = 2048, D = 1024, NH = 16, HD = 64;
static constexpr int M = BATCH * S; // 8192
static constexpr float KL = 0.045084220027780106f; // log2(e)/sqrt(1024)

__device__ __forceinline__ void gload16(const void* g, void* l) {
  __builtin_amdgcn_global_load_lds(
      (const __attribute__((address_space(1))) void*)g,
      (__attribute__((address_space(3))) void*)l, 16, 0, 0);
}

__device__ __forceinline__ float fexp2(float x) {
#if __has_builtin(__builtin_amdgcn_exp2f)
  return __builtin_amdgcn_exp2f(x);
#else
  return exp2f(x);
#endif
}

__device__ __forceinline__ u32 pack2(float a, float b) {
  union { bf16x2 h; u32 u; } c;
  c.h = (bf16x2){(bf16)a, (bf16)b};
  return c.u;
}

union U4 { u32 w[4]; bf16x8 v; };

// counted-vmcnt FENCED barrier: drain current tile's loads + ALL LDS ops,
// with a compiler memory fence (asm clobber) so no LDS op crosses it.
#define WAITV_BAR(n)                                                     \
  asm volatile("s_waitcnt vmcnt(" #n ") lgkmcnt(0)" ::: "memory");       \
  __builtin_amdgcn_s_barrier();                                          \
  __builtin_amdgcn_sched_barrier(0);

// plain fenced barrier (LDS producer->consumer across waves)
#define FENCE_BAR                                                        \
  asm volatile("s_waitcnt lgkmcnt(0)" ::: "memory");                     \
  __builtin_amdgcn_s_barrier();                                          \
  __builtin_amdgcn_sched_barrier(0);

// ---------------------------------------------------------------------------
// Kernel 1: convert fp32 weights -> bf16, transposed: Wt[n][k] = W[k][n]
// ---------------------------------------------------------------------------
__global__ __launch_bounds__(256) void wt_convert(
    const float* __restrict__ W0, const float* __restrict__ W1,
    const float* __restrict__ W2, const float* __restrict__ W3,
    bf16* __restrict__ WtAll)
{
  const float* W = blockIdx.y == 0 ? W0 : blockIdx.y == 1 ? W1
                 : blockIdx.y == 2 ? W2 : W3;
  bf16* dst = WtAll + (size_t)blockIdx.y * (D * D);
  int k0 = (blockIdx.x >> 4) * 64, n0 = (blockIdx.x & 15) * 64;
  __shared__ __align__(16) bf16 T[64][72];
  int tid = threadIdx.x;
#pragma unroll
  for (int i = 0; i < 4; ++i) {
    int c = tid + i * 256, r = c >> 4, seg = c & 15;
    float4 v = *reinterpret_cast<const float4*>(W + (size_t)(k0 + r) * D + n0 + seg * 4);
    T[seg * 4 + 0][r] = (bf16)v.x; T[seg * 4 + 1][r] = (bf16)v.y;
    T[seg * 4 + 2][r] = (bf16)v.z; T[seg * 4 + 3][r] = (bf16)v.w;
  }
  __syncthreads();
#pragma unroll
  for (int i = 0; i < 2; ++i) {
    int c = tid + i * 256, r = c >> 3, seg = c & 7;
    *reinterpret_cast<bf16x8*>(dst + (size_t)(n0 + r) * D + k0 + seg * 8) =
        *reinterpret_cast<const bf16x8*>(&T[r][seg * 8]);
  }
}

// ---------------------------------------------------------------------------
// Kernel 1b: convert query/key/value fp32 -> bf16 (contiguous Xb, 3 tensors).
// ---------------------------------------------------------------------------
__global__ __launch_bounds__(256) void x_convert(
    const float* __restrict__ X0, const float* __restrict__ X1,
    const float* __restrict__ X2, bf16* __restrict__ Y)
{
  int t = blockIdx.y;
  const float* X = t == 0 ? X0 : t == 1 ? X1 : X2;
  bf16* Yp = Y + (size_t)t * M * D;
  int idx = blockIdx.x * 256 + threadIdx.x;
#pragma unroll
  for (int i = 0; i < 4; ++i) {
    size_t j = (size_t)idx + (size_t)i * 524288;
    float4 v = reinterpret_cast<const float4*>(X)[j];
    bf16x4 o; o[0] = (bf16)v.x; o[1] = (bf16)v.y; o[2] = (bf16)v.z; o[3] = (bf16)v.w;
    reinterpret_cast<bf16x4*>(Yp)[j] = o;
  }
}

// ---------------------------------------------------------------------------
// Kernel 2: QKV projection GEMM. Q output pre-scaled by KL = log2e/sqrt(D).
// grid (512, 3), block 256 = 4 waves. XCD-chunked block swizzle.
// Q/K out: [bh][s][64]; V out transposed: [bh][64][s].
// ---------------------------------------------------------------------------
__global__ __launch_bounds__(256) void qkv_gemm(
    const bf16* __restrict__ Xb, const bf16* __restrict__ WtAll,
    const float* __restrict__ bq, const float* __restrict__ bk, const float* __restrict__ bv,
    bf16* __restrict__ Qb, bf16* __restrict__ Kb, bf16* __restrict__ Vtb)
{
  int v = blockIdx.y;
  const bf16*  X    = Xb + (size_t)v * M * D;
  const bf16*  Wt   = WtAll + (size_t)v * (D * D);
  const float* bias = v == 0 ? bq : v == 1 ? bk : bv;

  int x = blockIdx.x;
  int swz = (x & 7) * 64 + (x >> 3); // XCD-chunked, bijective for 512
  int mt = swz >> 3, nt = swz & 7;
  int m0 = mt * 128, n0 = nt * 128;
  int tid = threadIdx.x, lane = tid & 63, w = tid >> 6;
  int wm = (w >> 1) * 64, wn = (w & 1) * 64;
  int lr = lane & 15, lg = lane >> 4;

  __shared__ __align__(16) unsigned char smem[34816];
  auto As = reinterpret_cast<bf16(*)[128][32]>(smem);          // [2][128][32]
  auto Bs = reinterpret_cast<bf16(*)[128][32]>(smem + 16384);  // [2][128][32]

  f32x4 acc[4][4] = {};

  int srow = w * 32 + (lane >> 2);
  int scol = (lane & 3) * 8;

  auto stage = [&](int buf, int ks) {
    const bf16* ga = X + (size_t)(m0 + srow) * D + ks * 32 + scol;
    bf16* la = &As[buf][w * 32][0];
    gload16(ga, la);
    gload16(ga + 16 * D, la + 16 * 32);
    const bf16* gb = Wt + (size_t)(n0 + srow) * D + ks * 32 + scol;
    bf16* lb = &Bs[buf][w * 32][0];
    gload16(gb, lb);
    gload16(gb + 16 * D, lb + 16 * 32);
  };

  stage(0, 0);
  for (int ks = 0; ks < 32; ++ks) {
    __syncthreads();
    if (ks < 31) stage((ks + 1) & 1, ks + 1);
    int buf = ks & 1;
    bf16x8 af[4], bfr[4];
#pragma unroll
    for (int i = 0; i < 4; ++i)
      af[i] = *reinterpret_cast<const bf16x8*>(&As[buf][wm + i * 16 + lr][8 * lg]);
#pragma unroll
    for (int j = 0; j < 4; ++j)
      bfr[j] = *reinterpret_cast<const bf16x8*>(&Bs[buf][wn + j * 16 + lr][8 * lg]);
#pragma unroll
    for (int i = 0; i < 4; ++i)
#pragma unroll
      for (int j = 0; j < 4; ++j)
        acc[i][j] = MFMA(af[i], bfr[j], acc[i][j]);
  }
  __syncthreads();

  if (v < 2) { // Q/K: LDS [m][n] then coalesced store to [bh][s][64]
    bf16* Out = v == 0 ? Qb : Kb;
    float qs = v == 0 ? KL : 1.0f;
    auto Es = reinterpret_cast<bf16(*)[128]>(smem);
#pragma unroll
    for (int i = 0; i < 4; ++i)
#pragma unroll
      for (int j = 0; j < 4; ++j) {
        int n = wn + j * 16 + lr;
        float bias_n = bias[n0 + n];
#pragma unroll
        for (int r = 0; r < 4; ++r)
          Es[wm + i * 16 + 4 * lg + r][n] = (bf16)((acc[i][j][r] + bias_n) * qs);
      }
    __syncthreads();
#pragma unroll
    for (int i = 0; i < 8; ++i) {
      int c = tid + i * 256, r = c >> 4, seg = c & 15;
      int mg = m0 + r, b = mg >> 11, s = mg & 2047;
      int ng = n0 + seg * 8, h = ng >> 6, d = ng & 63;
      *reinterpret_cast<bf16x8*>(Out + (((size_t)(b * NH + h)) * S + s) * HD + d) =
          *reinterpret_cast<const bf16x8*>(&Es[r][seg * 8]);
    }
  } else { // V: LDS [n][m] (transposed) then coalesced store to [bh][64][s]
    auto Es = reinterpret_cast<bf16(*)[136]>(smem);
#pragma unroll
    for (int i = 0; i < 4; ++i)
#pragma unroll
      for (int j = 0; j < 4; ++j) {
        int n = wn + j * 16 + lr;
        float bias_n = bias[n0 + n];
        bf16x4 t;
#pragma unroll
        for (int r = 0; r < 4; ++r) t[r] = (bf16)(acc[i][j][r] + bias_n);
        *reinterpret_cast<bf16x4*>(&Es[n][wm + i * 16 + 4 * lg]) = t;
      }
    __syncthreads();
#pragma unroll
    for (int i = 0; i < 8; ++i) {
      int c = tid + i * 256, r = c >> 4, seg = c & 15;
      int ng = n0 + r, h = ng >> 6, d = ng & 63;
      int mg = m0 + seg * 8, b = mg >> 11, s = mg & 2047;
      *reinterpret_cast<bf16x8*>(Vtb + (((size_t)(b * NH + h)) * HD + d) * S + s) =
          *reinterpret_cast<const bf16x8*>(&Es[r][seg * 8]);
    }
  }
}

// ---------------------------------------------------------------------------
// Kernel 3: fused attention, 3-phase merged pipeline over q-tile pairs.
// Block = (b,h) x 128 q-rows (tiles X, Y of 64). 4 waves: qh x kh.
// Phase 1: sums(X).  Phase 2: B(X) + A(Y) in ONE k-loop.  Phase 3: B(Y).
// R9 experiment: storeP uses PLAIN stores (L2 write-combining) instead of
// nontemporal — NT bypasses L2 and appears to cap the 1.07 GB write stream.
// ---------------------------------------------------------------------------
__global__ __launch_bounds__(256) void attn_kernel(
    const bf16* __restrict__ Qb, const bf16* __restrict__ Kb, const bf16* __restrict__ Vtb,
    float* __restrict__ attn_out, bf16* __restrict__ ctx)
{
  int xx = blockIdx.x;                     // 1024 blocks
  int xcd = xx & 7, r8 = xx >> 3;          // r8 in [0,128)
  int bh = xcd + 8 * (r8 >> 4);            // 8 sequential heads per XCD
  int qp = r8 & 15;                        // q-pair index (128 rows)
  int tid = threadIdx.x, lane = tid & 63, w = tid >> 6;
  int q32 = lane & 31, hi = lane >> 5;
  int qh = w & 1, kh = w >> 1;

  __shared__ __align__(16) bf16 Ks[2][64][64];
  __shared__ __align__(16) bf16 Vs[2][64][64];
  __shared__ __align__(16) float Ps[64][68];   // P tile / ctx scratch
  __shared__ float sums[2][64];

  int qrowX = qp * 128 + qh * 32 + q32;
  const bf16* QrowX = Qb + ((size_t)bh * S + qrowX) * HD;
  const bf16* QrowY = QrowX + (size_t)64 * HD;
  bf16x8 qregX[4], qregY[4];
#pragma unroll
  for (int c = 0; c < 4; ++c) {
    qregX[c] = *reinterpret_cast<const bf16x8*>(QrowX + c * 16 + 8 * hi);
    qregY[c] = *reinterpret_cast<const bf16x8*>(QrowY + c * 16 + 8 * hi);
  }

  auto stageK = [&](int buf, int kc) {
    const bf16* base = Kb + ((size_t)bh * S + kc * 64) * HD;
#pragma unroll
    for (int i = 0; i < 2; ++i) {
      int c = i * 256 + tid, row = c >> 3, j = c & 7;
      gload16(base + row * HD + 8 * (j ^ (row & 7)),
              reinterpret_cast<bf16*>(&Ks[buf][0][0]) + c * 8);
    }
  };
  auto stageV = [&](int buf, int kc) {
    const bf16* base = Vtb + (size_t)bh * HD * S + kc * 64;
#pragma unroll
    for (int i = 0; i < 2; ++i) {
      int c = i * 256 + tid, row = c >> 3, j = c & 7;
      gload16(base + (size_t)row * S + 8 * (j ^ (row & 7)),
              reinterpret_cast<bf16*>(&Vs[buf][0][0]) + c * 8);
    }
  };

  int krow = kh * 32 + q32, ks7 = krow & 7;

  // ---- phase 1: row sums of exp2(s) for X (K-only) ----
  float xs[4] = {0.f, 0.f, 0.f, 0.f};
  stageK(0, 0);
  for (int kc = 0; kc < 32; ++kc) {
    if (kc < 31) {
      stageK((kc + 1) & 1, kc + 1);
      WAITV_BAR(2)
    } else {
      WAITV_BAR(0)
    }
    int buf = kc & 1;
    f32x16 sa = {};
#pragma unroll
    for (int c = 0; c < 4; ++c) {
      bf16x8 kf = *reinterpret_cast<const bf16x8*>(&Ks[buf][krow][8 * ((2 * c + hi) ^ ks7)]);
      sa = MFMA32(kf, qregX[c], sa);
    }
#pragma unroll
    for (int r = 0; r < 16; ++r) xs[r & 3] += fexp2(sa[r]);
    FENCE_BAR
  }
  {
    float lrun = (xs[0] + xs[1]) + (xs[2] + xs[3]);
    lrun += __shfl_xor(lrun, 32);
    if (hi == 0) sums[kh][qh * 32 + q32] = lrun;
  }
  __syncthreads();
  float lg2lX = __log2f(sums[0][qh * 32 + q32] + sums[1][qh * 32 + q32]);

  f32x16 oaccA = {}, oaccB = {};
  float ys[4] = {0.f, 0.f, 0.f, 0.f};
  float* ablkX = attn_out + ((size_t)bh * S + qp * 128) * S;
  float* ablkY = ablkX + (size_t)64 * S;
  int prow = tid >> 2, pc0 = (tid & 3) * 4;

  auto storeP = [&](float* ablk, int kc) {
    float* dst = ablk + (size_t)prow * S + kc * 64 + pc0;
#pragma unroll
    for (int i = 0; i < 4; ++i)
      *reinterpret_cast<f32x4*>(dst + 16 * i) =
          *reinterpret_cast<const f32x4*>(&Ps[prow][pc0 + 16 * i]);
  };

  auto pv_accum = [&](int buf, const u32* pku) {
#pragma unroll
    for (int c2 = 0; c2 < 2; ++c2) {
      u32 myw0 = hi ? pku[4 * c2 + 2] : pku[4 * c2 + 0];
      u32 myw1 = hi ? pku[4 * c2 + 3] : pku[4 * c2 + 1];
      u32 sdw0 = hi ? pku[4 * c2 + 0] : pku[4 * c2 + 2];
      u32 sdw1 = hi ? pku[4 * c2 + 1] : pku[4 * c2 + 3];
      u32 r0 = __shfl_xor(sdw0, 32);
      u32 r1 = __shfl_xor(sdw1, 32);
      U4 f;
      f.w[0] = hi ? r0 : myw0;
      f.w[1] = hi ? r1 : myw1;
      f.w[2] = hi ? myw0 : r0;
      f.w[3] = hi ? myw1 : r1;
      {
        int vrow = q32, vs7 = vrow & 7;      // d-half 0
        bf16x8 vf = *reinterpret_cast<const bf16x8*>(
            &Vs[buf][vrow][8 * ((4 * kh + 2 * c2 + hi) ^ vs7)]);
        oaccA = MFMA32(f.v, vf, oaccA);
      }
      {
        int vrow = 32 + q32, vs7 = vrow & 7; // d-half 1
        bf16x8 vf = *reinterpret_cast<const bf16x8*>(
            &Vs[buf][vrow][8 * ((4 * kh + 2 * c2 + hi) ^ vs7)]);
        oaccB = MFMA32(f.v, vf, oaccB);
      }
    }
  };

  // phase-2 body: B(X) + A(Y), shared kf reads
  auto merged = [&](int buf) {
    f32x16 saX = {}, saY = {};
#pragma unroll
    for (int c = 0; c < 4; ++c) {
      bf16x8 kf = *reinterpret_cast<const bf16x8*>(&Ks[buf][krow][8 * ((2 * c + hi) ^ ks7)]);
      saX = MFMA32(kf, qregX[c], saX);
      saY = MFMA32(kf, qregY[c], saY);
    }
    u32 pku[8];
#pragma unroll
    for (int rq = 0; rq < 4; ++rq) {
      f32x4 pv;
#pragma unroll
      for (int j = 0; j < 4; ++j) pv[j] = fexp2(saX[rq * 4 + j] - lg2lX);
      *reinterpret_cast<f32x4*>(&Ps[qh * 32 + q32][kh * 32 + 8 * rq + 4 * hi]) = pv;
      pku[rq * 2 + 0] = pack2(pv[0], pv[1]);
      pku[rq * 2 + 1] = pack2(pv[2], pv[3]);
    }
    pv_accum(buf, pku);
#pragma unroll
    for (int r = 0; r < 16; ++r) ys[r & 3] += fexp2(saY[r]);
  };

  // ---- phase 2 ----
  stageK(0, 0); stageV(0, 0);
  stageK(1, 1); stageV(1, 1);
  WAITV_BAR(4)
  merged(0);
  FENCE_BAR
  storeP(ablkX, 0);
  for (int kc = 1; kc < 32; ++kc) {
    if (kc < 31) {
      stageK((kc + 1) & 1, kc + 1);
      stageV((kc + 1) & 1, kc + 1);
      WAITV_BAR(8)
    } else {
      WAITV_BAR(4)
    }
    merged(kc & 1);
    FENCE_BAR
    storeP(ablkX, kc);
  }

  // combine Y sums
  {
    float lrY = (ys[0] + ys[1]) + (ys[2] + ys[3]);
    lrY += __shfl_xor(lrY, 32);
    if (hi == 0) sums[kh][qh * 32 + q32] = lrY;
  }
  __syncthreads();
  float lg2lY = __log2f(sums[0][qh * 32 + q32] + sums[1][qh * 32 + q32]);

  // ctx writer via Ps scratch (kh==1 deposit, kh==0 combine, all store)
  auto ctx_write = [&](int qgbase) {
    __syncthreads();
    if (kh == 1) {
#pragma unroll
      for (int reg = 0; reg < 16; ++reg) {
        int qloc = (reg & 3) + 8 * (reg >> 2) + 4 * hi;
        Ps[qh * 32 + qloc][q32]      = oaccA[reg];
        Ps[qh * 32 + qloc][32 + q32] = oaccB[reg];
      }
    }
    __syncthreads();
    if (kh == 0) {
#pragma unroll
      for (int reg = 0; reg < 16; ++reg) {
        int qloc = (reg & 3) + 8 * (reg >> 2) + 4 * hi;
        Ps[qh * 32 + qloc][q32]      += oaccA[reg];
        Ps[qh * 32 + qloc][32 + q32] += oaccB[reg];
      }
    }
    __syncthreads();
    int b = bh >> 4, h = bh & 15;
    int row = tid >> 2, cseg = (tid & 3) * 16;
    f32x4 v0 = *reinterpret_cast<const f32x4*>(&Ps[row][cseg]);
    f32x4 v1 = *reinterpret_cast<const f32x4*>(&Ps[row][cseg + 4]);
    f32x4 v2 = *reinterpret_cast<const f32x4*>(&Ps[row][cseg + 8]);
    f32x4 v3 = *reinterpret_cast<const f32x4*>(&Ps[row][cseg + 12]);
    bf16x8 o0, o1;
#pragma unroll
    for (int j = 0; j < 4; ++j) {
      o0[j] = (bf16)v0[j]; o0[4 + j] = (bf16)v1[j];
      o1[j] = (bf16)v2[j]; o1[4 + j] = (bf16)v3[j];
    }
    bf16* cp = ctx + ((size_t)b * S + qgbase + row) * D + h * HD + cseg;
    *reinterpret_cast<bf16x8*>(cp)     = o0;
    *reinterpret_cast<bf16x8*>(cp + 8) = o1;
  };

  ctx_write(qp * 128);
#pragma unroll
  for (int r = 0; r < 16; ++r) { oaccA[r] = 0.f; oaccB[r] = 0.f; }

  // phase-3 body: B(Y)
  auto bodyY = [&](int buf) {
    f32x16 saY = {};
#pragma unroll
    for (int c = 0; c < 4; ++c) {
      bf16x8 kf = *reinterpret_cast<const bf16x8*>(&Ks[buf][krow][8 * ((2 * c + hi) ^ ks7)]);
      saY = MFMA32(kf, qregY[c], saY);
    }
    u32 pku[8];
#pragma unroll
    for (int rq = 0; rq < 4; ++rq) {
      f32x4 pv;
#pragma unroll
      for (int j = 0; j < 4; ++j) pv[j] = fexp2(saY[rq * 4 + j] - lg2lY);
      *reinterpret_cast<f32x4*>(&Ps[qh * 32 + q32][kh * 32 + 8 * rq + 4 * hi]) = pv;
      pku[rq * 2 + 0] = pack2(pv[0], pv[1]);
      pku[rq * 2 + 1] = pack2(pv[2], pv[3]);
    }
    pv_accum(buf, pku);
  };

  // ---- phase 3 ----
  stageK(0, 0); stageV(0, 0);
  stageK(1, 1); stageV(1, 1);
  WAITV_BAR(4)
  bodyY(0);
  FENCE_BAR
  storeP(ablkY, 0);
  for (int kc = 1; kc < 32; ++kc) {
    if (kc < 31) {
      stageK((kc + 1) & 1, kc + 1);
      stageV((kc + 1) & 1, kc + 1);
      WAITV_BAR(8)
    } else {
      WAITV_BAR(4)
    }
    bodyY(kc & 1);
    FENCE_BAR
    storeP(ablkY, kc);
  }

  ctx_write(qp * 128 + 64);
}

// ---------------------------------------------------------------------------
// Kernel 4: output projection. out(fp32) = ctx(bf16) @ Wo + bo.
// grid (512), block 256. XCD-chunked swizzle.
// ---------------------------------------------------------------------------
__global__ __launch_bounds__(256) void out_gemm(
    const bf16* __restrict__ ctx, const bf16* __restrict__ Wto,
    const float* __restrict__ bo, float* __restrict__ Out)
{
  int x = blockIdx.x;
  int swz = (x & 7) * 64 + (x >> 3);
  int mt = swz >> 3, nt = swz & 7;
  int m0 = mt * 128, n0 = nt * 128;
  int tid = threadIdx.x, lane = tid & 63, w = tid >> 6;
  int wm = (w >> 1) * 64, wn = (w & 1) * 64;
  int lr = lane & 15, lg = lane >> 4;

  __shared__ __align__(16) bf16 As[2][128][32];
  __shared__ __align__(16) bf16 Bs[2][128][32];

  f32x4 acc[4][4] = {};

  int srow = w * 32 + (lane >> 2);
  int scol = (lane & 3) * 8;

  auto stage = [&](int buf, int ks) {
    const bf16* ga = ctx + (size_t)(m0 + srow) * D + ks * 32 + scol;
    bf16* la = &As[buf][w * 32][0];
    gload16(ga, la);
    gload16(ga + 16 * D, la + 16 * 32);
    const bf16* gb = Wto + (size_t)(n0 + srow) * D + ks * 32 + scol;
    bf16* lb = &Bs[buf][w * 32][0];
    gload16(gb, lb);
    gload16(gb + 16 * D, lb + 16 * 32);
  };

  stage(0, 0);
  for (int ks = 0; ks < 32; ++ks) {
    __syncthreads();
    if (ks < 31) stage((ks + 1) & 1, ks + 1);
    int buf = ks & 1;
    bf16x8 af[4], bfr[4];
#pragma unroll
    for (int i = 0; i < 4; ++i)
      af[i] = *reinterpret_cast<const bf16x8*>(&As[buf][wm + i * 16 + lr][8 * lg]);
#pragma unroll
    for (int j = 0; j < 4; ++j)
      bfr[j] = *reinterpret_cast<const bf16x8*>(&Bs[buf][wn + j * 16 + lr][8 * lg]);
#pragma unroll
    for (int i = 0; i < 4; ++i)
#pragma unroll
      for (int j = 0; j < 4; ++j)
        acc[i][j] = MFMA(af[i], bfr[j], acc[i][j]);
  }

#pragma unroll
  for (int i = 0; i < 4; ++i)
#pragma unroll
    for (int j = 0; j < 4; ++j) {
      int n = n0 + wn + j * 16 + lr;
      float bias_n = bo[n];
#pragma unroll
      for (int r = 0; r < 4; ++r)
        Out[(size_t)(m0 + wm + i * 16 + 4 * lg + r) * D + n] = acc[i][j][r] + bias_n;
    }
}

// ---------------------------------------------------------------------------
extern "C" void kernel_launch(void* const* d_in, const int* in_sizes, int n_in,
                              void* d_out, int out_size, void* d_ws, size_t ws_size,
                              hipStream_t stream)
{
  const float* query = (const float*)d_in[0];
  const float* key   = (const float*)d_in[1];
  const float* value = (const float*)d_in[2];
  const float* Wq = (const float*)d_in[3]; const float* bq = (const float*)d_in[4];
  const float* Wk = (const float*)d_in[5]; const float* bk = (const float*)d_in[6];
  const float* Wv = (const float*)d_in[7]; const float* bv = (const float*)d_in[8];
  const float* Wo = (const float*)d_in[9]; const float* bo = (const float*)d_in[10];

  float* out  = (float*)d_out;
  float* attn = out + (size_t)M * D; // 8388608 floats

  char* ws = (char*)d_ws;
  const size_t MiB = 1048576;
  bf16* WtAll = (bf16*)ws;                    // 8 MiB (4 x 1024x1024)
  bf16* Xb    = (bf16*)(ws + 8 * MiB);        // 48 MiB (3 x 8192x1024)
  bf16* Qb    = (bf16*)(ws + 56 * MiB);       // 16 MiB
  bf16* Kb    = (bf16*)(ws + 72 * MiB);       // 16 MiB
  bf16* Vtb   = (bf16*)(ws + 88 * MiB);       // 16 MiB
  bf16* ctx   = Xb;                           // reuse: Xb dead after qkv_gemm

  wt_convert<<<dim3(256, 4), 256, 0, stream>>>(Wq, Wk, Wv, Wo, WtAll);
  x_convert<<<dim3(2048, 3), 256, 0, stream>>>(query, key, value, Xb);
  qkv_gemm<<<dim3(512, 3), 256, 0, stream>>>(Xb, WtAll, bq, bk, bv, Qb, Kb, Vtb);
  attn_kernel<<<dim3(1024), 256, 0, stream>>>(Qb, Kb, Vtb, attn, ctx);
  out_gemm<<<dim3(512), 256, 0, stream>>>(ctx, WtAll + (size_t)3 * D * D, bo, out);
}

// Round 10
// 440.204 us; speedup vs baseline: 1.3432x; 1.3432x over previous
//
#include <hip/hip_runtime.h>
#include <hip/hip_bf16.h>

typedef __bf16 bf16;
typedef __bf16 bf16x8 __attribute__((ext_vector_type(8)));
typedef __bf16 bf16x4 __attribute__((ext_vector_type(4)));
typedef __bf16 bf16x2 __attribute__((ext_vector_type(2)));
typedef float  f32x4  __attribute__((ext_vector_type(4)));
typedef float  f32x16 __attribute__((ext_vector_type(16)));
typedef unsigned int u32;

#define MFMA(A, B, C)   __builtin_amdgcn_mfma_f32_16x16x32_bf16((A), (B), (C), 0, 0, 0)
#define MFMA32(A, B, C) __builtin_amdgcn_mfma_f32_32x32x16_bf16((A), (B), (C), 0, 0, 0)

static constexpr int BATCH = 4, S = 2048, D = 1024, NH = 16, HD = 64;
static constexpr int M = BATCH * S; // 8192
static constexpr float KL = 0.045084220027780106f; // log2(e)/sqrt(1024)

__device__ __forceinline__ void gload16(const void* g, void* l) {
  __builtin_amdgcn_global_load_lds(
      (const __attribute__((address_space(1))) void*)g,
      (__attribute__((address_space(3))) void*)l, 16, 0, 0);
}

__device__ __forceinline__ float fexp2(float x) {
#if __has_builtin(__builtin_amdgcn_exp2f)
  return __builtin_amdgcn_exp2f(x);
#else
  return exp2f(x);
#endif
}

__device__ __forceinline__ u32 pack2(float a, float b) {
  union { bf16x2 h; u32 u; } c;
  c.h = (bf16x2){(bf16)a, (bf16)b};
  return c.u;
}

union U4 { u32 w[4]; bf16x8 v; };

// counted-vmcnt FENCED barrier: drain current tile's loads + ALL LDS ops,
// with a compiler memory fence so no LDS/VM op is reordered across it.
#define WAITV_BAR(n)                                                     \
  asm volatile("s_waitcnt vmcnt(" #n ") lgkmcnt(0)" ::: "memory");       \
  __builtin_amdgcn_s_barrier();                                          \
  __builtin_amdgcn_sched_barrier(0);

// plain fenced barrier (LDS producer->consumer across waves)
#define FENCE_BAR                                                        \
  asm volatile("s_waitcnt lgkmcnt(0)" ::: "memory");                     \
  __builtin_amdgcn_s_barrier();                                          \
  __builtin_amdgcn_sched_barrier(0);

// ---------------------------------------------------------------------------
// Kernel 1: fused converts.
// blocks [0, 6144): X fp32->bf16 (query/key/value -> Xb, 2048 blocks each)
// blocks [6144, 7168): W fp32->bf16 transposed (Wt[n][k] = W[k][n], 256 x 4)
// ---------------------------------------------------------------------------
__global__ __launch_bounds__(256) void convert_all(
    const float* __restrict__ X0, const float* __restrict__ X1,
    const float* __restrict__ X2,
    const float* __restrict__ W0, const float* __restrict__ W1,
    const float* __restrict__ W2, const float* __restrict__ W3,
    bf16* __restrict__ Xb, bf16* __restrict__ WtAll)
{
  int blk = blockIdx.x;
  int tid = threadIdx.x;
  if (blk < 6144) {
    int t = blk >> 11;              // tensor 0..2
    int bx = blk & 2047;
    const float* X = t == 0 ? X0 : t == 1 ? X1 : X2;
    bf16* Yp = Xb + (size_t)t * M * D;
    int idx = bx * 256 + tid;
#pragma unroll
    for (int i = 0; i < 4; ++i) {
      size_t j = (size_t)idx + (size_t)i * 524288;
      float4 v = reinterpret_cast<const float4*>(X)[j];
      bf16x4 o; o[0] = (bf16)v.x; o[1] = (bf16)v.y; o[2] = (bf16)v.z; o[3] = (bf16)v.w;
      reinterpret_cast<bf16x4*>(Yp)[j] = o;
    }
  } else {
    int wb = blk - 6144;            // 0..1023
    int wy = wb >> 8;               // weight 0..3
    int bx = wb & 255;
    const float* W = wy == 0 ? W0 : wy == 1 ? W1 : wy == 2 ? W2 : W3;
    bf16* dst = WtAll + (size_t)wy * (D * D);
    int k0 = (bx >> 4) * 64, n0 = (bx & 15) * 64;
    __shared__ __align__(16) bf16 T[64][72];
#pragma unroll
    for (int i = 0; i < 4; ++i) {
      int c = tid + i * 256, r = c >> 4, seg = c & 15;
      float4 v = *reinterpret_cast<const float4*>(W + (size_t)(k0 + r) * D + n0 + seg * 4);
      T[seg * 4 + 0][r] = (bf16)v.x; T[seg * 4 + 1][r] = (bf16)v.y;
      T[seg * 4 + 2][r] = (bf16)v.z; T[seg * 4 + 3][r] = (bf16)v.w;
    }
    __syncthreads();
#pragma unroll
    for (int i = 0; i < 2; ++i) {
      int c = tid + i * 256, r = c >> 3, seg = c & 7;
      *reinterpret_cast<bf16x8*>(dst + (size_t)(n0 + r) * D + k0 + seg * 8) =
          *reinterpret_cast<const bf16x8*>(&T[r][seg * 8]);
    }
  }
}

// ---------------------------------------------------------------------------
// Kernel 2: QKV projection GEMM. Q output pre-scaled by KL = log2e/sqrt(D).
// grid (512, 3), block 256 = 4 waves. XCD-chunked block swizzle.
// Q/K out: [bh][s][64]; V out transposed: [bh][64][s].
// ---------------------------------------------------------------------------
__global__ __launch_bounds__(256) void qkv_gemm(
    const bf16* __restrict__ Xb, const bf16* __restrict__ WtAll,
    const float* __restrict__ bq, const float* __restrict__ bk, const float* __restrict__ bv,
    bf16* __restrict__ Qb, bf16* __restrict__ Kb, bf16* __restrict__ Vtb)
{
  int v = blockIdx.y;
  const bf16*  X    = Xb + (size_t)v * M * D;
  const bf16*  Wt   = WtAll + (size_t)v * (D * D);
  const float* bias = v == 0 ? bq : v == 1 ? bk : bv;

  int x = blockIdx.x;
  int swz = (x & 7) * 64 + (x >> 3); // XCD-chunked, bijective for 512
  int mt = swz >> 3, nt = swz & 7;
  int m0 = mt * 128, n0 = nt * 128;
  int tid = threadIdx.x, lane = tid & 63, w = tid >> 6;
  int wm = (w >> 1) * 64, wn = (w & 1) * 64;
  int lr = lane & 15, lg = lane >> 4;

  __shared__ __align__(16) unsigned char smem[34816];
  auto As = reinterpret_cast<bf16(*)[128][32]>(smem);          // [2][128][32]
  auto Bs = reinterpret_cast<bf16(*)[128][32]>(smem + 16384);  // [2][128][32]

  f32x4 acc[4][4] = {};

  int srow = w * 32 + (lane >> 2);
  int scol = (lane & 3) * 8;

  auto stage = [&](int buf, int ks) {
    const bf16* ga = X + (size_t)(m0 + srow) * D + ks * 32 + scol;
    bf16* la = &As[buf][w * 32][0];
    gload16(ga, la);
    gload16(ga + 16 * D, la + 16 * 32);
    const bf16* gb = Wt + (size_t)(n0 + srow) * D + ks * 32 + scol;
    bf16* lb = &Bs[buf][w * 32][0];
    gload16(gb, lb);
    gload16(gb + 16 * D, lb + 16 * 32);
  };

  stage(0, 0);
  for (int ks = 0; ks < 32; ++ks) {
    __syncthreads();
    if (ks < 31) stage((ks + 1) & 1, ks + 1);
    int buf = ks & 1;
    bf16x8 af[4], bfr[4];
#pragma unroll
    for (int i = 0; i < 4; ++i)
      af[i] = *reinterpret_cast<const bf16x8*>(&As[buf][wm + i * 16 + lr][8 * lg]);
#pragma unroll
    for (int j = 0; j < 4; ++j)
      bfr[j] = *reinterpret_cast<const bf16x8*>(&Bs[buf][wn + j * 16 + lr][8 * lg]);
#pragma unroll
    for (int i = 0; i < 4; ++i)
#pragma unroll
      for (int j = 0; j < 4; ++j)
        acc[i][j] = MFMA(af[i], bfr[j], acc[i][j]);
  }
  __syncthreads();

  if (v < 2) { // Q/K: LDS [m][n] then coalesced store to [bh][s][64]
    bf16* Out = v == 0 ? Qb : Kb;
    float qs = v == 0 ? KL : 1.0f;
    auto Es = reinterpret_cast<bf16(*)[128]>(smem);
#pragma unroll
    for (int i = 0; i < 4; ++i)
#pragma unroll
      for (int j = 0; j < 4; ++j) {
        int n = wn + j * 16 + lr;
        float bias_n = bias[n0 + n];
#pragma unroll
        for (int r = 0; r < 4; ++r)
          Es[wm + i * 16 + 4 * lg + r][n] = (bf16)((acc[i][j][r] + bias_n) * qs);
      }
    __syncthreads();
#pragma unroll
    for (int i = 0; i < 8; ++i) {
      int c = tid + i * 256, r = c >> 4, seg = c & 15;
      int mg = m0 + r, b = mg >> 11, s = mg & 2047;
      int ng = n0 + seg * 8, h = ng >> 6, d = ng & 63;
      *reinterpret_cast<bf16x8*>(Out + (((size_t)(b * NH + h)) * S + s) * HD + d) =
          *reinterpret_cast<const bf16x8*>(&Es[r][seg * 8]);
    }
  } else { // V: LDS [n][m] (transposed) then coalesced store to [bh][64][s]
    auto Es = reinterpret_cast<bf16(*)[136]>(smem);
#pragma unroll
    for (int i = 0; i < 4; ++i)
#pragma unroll
      for (int j = 0; j < 4; ++j) {
        int n = wn + j * 16 + lr;
        float bias_n = bias[n0 + n];
        bf16x4 t;
#pragma unroll
        for (int r = 0; r < 4; ++r) t[r] = (bf16)(acc[i][j][r] + bias_n);
        *reinterpret_cast<bf16x4*>(&Es[n][wm + i * 16 + 4 * lg]) = t;
      }
    __syncthreads();
#pragma unroll
    for (int i = 0; i < 8; ++i) {
      int c = tid + i * 256, r = c >> 4, seg = c & 15;
      int ng = n0 + r, h = ng >> 6, d = ng & 63;
      int mg = m0 + seg * 8, b = mg >> 11, s = mg & 2047;
      *reinterpret_cast<bf16x8*>(Vtb + (((size_t)(b * NH + h)) * HD + d) * S + s) =
          *reinterpret_cast<const bf16x8*>(&Es[r][seg * 8]);
    }
  }
}

// ---------------------------------------------------------------------------
// Kernel 3: fused attention (R6 structure + fenced barriers + NT stores).
// Block = (b,h) x 64 q-rows. 4 waves: (qh = w&1) q-half, (kh = w>>1) key-half.
// Pass A: exp2-sum (4-partial accumulators). Pass B: recompute, P -> LDS
// (Ps f32 [64][68]), coalesced NT store phase (full 64B lines), PV MFMA via
// packed bf16 + shfl_xor(32). NT stores bypass L2 -> K/V stay resident (R9).
// ---------------------------------------------------------------------------
__global__ __launch_bounds__(256) void attn_kernel(
    const bf16* __restrict__ Qb, const bf16* __restrict__ Kb, const bf16* __restrict__ Vtb,
    float* __restrict__ attn_out, bf16* __restrict__ ctx)
{
  int xx = blockIdx.x;
  int xcd = xx & 7, r8 = xx >> 3;
  int bh = xcd + 8 * (r8 >> 5);            // 8 sequential heads per XCD
  int qb = r8 & 31;
  int tid = threadIdx.x, lane = tid & 63, w = tid >> 6;
  int q32 = lane & 31, hi = lane >> 5;
  int qh = w & 1, kh = w >> 1;

  __shared__ __align__(16) bf16 Ks[2][64][64];
  __shared__ __align__(16) bf16 Vs[2][64][64];
  __shared__ __align__(16) float Ps[64][68];   // P tile f32, padded stride
  __shared__ float sums[2][64];

  int q_row = qb * 64 + qh * 32 + q32;
  const bf16* Qrow = Qb + ((size_t)bh * S + q_row) * HD;
  bf16x8 qreg[4];
#pragma unroll
  for (int c = 0; c < 4; ++c)
    qreg[c] = *reinterpret_cast<const bf16x8*>(Qrow + c * 16 + 8 * hi);

  auto stageK = [&](int buf, int kc) {
    const bf16* base = Kb + ((size_t)bh * S + kc * 64) * HD;
#pragma unroll
    for (int i = 0; i < 2; ++i) {
      int c = i * 256 + tid, row = c >> 3, j = c & 7;
      gload16(base + row * HD + 8 * (j ^ (row & 7)),
              reinterpret_cast<bf16*>(&Ks[buf][0][0]) + c * 8);
    }
  };
  auto stageV = [&](int buf, int kc) {
    const bf16* base = Vtb + (size_t)bh * HD * S + kc * 64;
#pragma unroll
    for (int i = 0; i < 2; ++i) {
      int c = i * 256 + tid, row = c >> 3, j = c & 7;
      gload16(base + (size_t)row * S + 8 * (j ^ (row & 7)),
              reinterpret_cast<bf16*>(&Vs[buf][0][0]) + c * 8);
    }
  };

  int krow = kh * 32 + q32, ks7 = krow & 7;

  // ---- pass A: row sum of exp2(s) over this wave's key-half ----
  float xs[4] = {0.f, 0.f, 0.f, 0.f};
  stageK(0, 0);
  for (int kc = 0; kc < 32; ++kc) {
    if (kc < 31) {
      stageK((kc + 1) & 1, kc + 1);
      WAITV_BAR(2)
    } else {
      WAITV_BAR(0)
    }
    int buf = kc & 1;
    f32x16 sa = {};
#pragma unroll
    for (int c = 0; c < 4; ++c) {
      bf16x8 kf = *reinterpret_cast<const bf16x8*>(&Ks[buf][krow][8 * ((2 * c + hi) ^ ks7)]);
      sa = MFMA32(kf, qreg[c], sa);
    }
#pragma unroll
    for (int r = 0; r < 16; ++r) xs[r & 3] += fexp2(sa[r]);
    FENCE_BAR
  }
  float lrun = (xs[0] + xs[1]) + (xs[2] + xs[3]);
  lrun += __shfl_xor(lrun, 32);            // combine hi pair (same q)
  if (hi == 0) sums[kh][qh * 32 + q32] = lrun;
  __syncthreads();
  float lg2l = __log2f(sums[0][qh * 32 + q32] + sums[1][qh * 32 + q32]);

  // ---- pass B: recompute, P -> LDS, PV accumulate; coalesced NT store ----
  f32x16 oaccA = {}, oaccB = {};           // d-halves 0,1 (named: rule #20)
  float* ablk = attn_out + ((size_t)bh * S + qb * 64) * S;

  auto computeB = [&](int buf) {
    f32x16 sa = {};
#pragma unroll
    for (int c = 0; c < 4; ++c) {
      bf16x8 kf = *reinterpret_cast<const bf16x8*>(&Ks[buf][krow][8 * ((2 * c + hi) ^ ks7)]);
      sa = MFMA32(kf, qreg[c], sa);
    }
    u32 pku[8];
#pragma unroll
    for (int rq = 0; rq < 4; ++rq) {
      f32x4 pv;
#pragma unroll
      for (int j = 0; j < 4; ++j) pv[j] = fexp2(sa[rq * 4 + j] - lg2l);
      *reinterpret_cast<f32x4*>(&Ps[qh * 32 + q32][kh * 32 + 8 * rq + 4 * hi]) = pv;
      pku[rq * 2 + 0] = pack2(pv[0], pv[1]);
      pku[rq * 2 + 1] = pack2(pv[2], pv[3]);
    }
#pragma unroll
    for (int c2 = 0; c2 < 2; ++c2) {
      u32 myw0 = hi ? pku[4 * c2 + 2] : pku[4 * c2 + 0];
      u32 myw1 = hi ? pku[4 * c2 + 3] : pku[4 * c2 + 1];
      u32 sdw0 = hi ? pku[4 * c2 + 0] : pku[4 * c2 + 2];
      u32 sdw1 = hi ? pku[4 * c2 + 1] : pku[4 * c2 + 3];
      u32 r0 = __shfl_xor(sdw0, 32);
      u32 r1 = __shfl_xor(sdw1, 32);
      U4 f;
      f.w[0] = hi ? r0 : myw0;
      f.w[1] = hi ? r1 : myw1;
      f.w[2] = hi ? myw0 : r0;
      f.w[3] = hi ? myw1 : r1;
      {
        int vrow = q32, vs7 = vrow & 7;      // d-half 0
        bf16x8 vf = *reinterpret_cast<const bf16x8*>(
            &Vs[buf][vrow][8 * ((4 * kh + 2 * c2 + hi) ^ vs7)]);
        oaccA = MFMA32(f.v, vf, oaccA);
      }
      {
        int vrow = 32 + q32, vs7 = vrow & 7; // d-half 1
        bf16x8 vf = *reinterpret_cast<const bf16x8*>(
            &Vs[buf][vrow][8 * ((4 * kh + 2 * c2 + hi) ^ vs7)]);
        oaccB = MFMA32(f.v, vf, oaccB);
      }
    }
  };

  // coalesced NT attn store: per instr, each 4-lane group writes one full
  // contiguous 64B line (16 full lines / instruction).
  int prow = tid >> 2, pc0 = (tid & 3) * 4;
  auto storeP = [&](int kc) {
    float* dst = ablk + (size_t)prow * S + kc * 64 + pc0;
#pragma unroll
    for (int i = 0; i < 4; ++i)
      __builtin_nontemporal_store(
          *reinterpret_cast<const f32x4*>(&Ps[prow][pc0 + 16 * i]),
          reinterpret_cast<f32x4*>(dst + 16 * i));
  };

  // prologue + peeled iter 0 (no stores in flight yet)
  stageK(0, 0); stageV(0, 0);
  stageK(1, 1); stageV(1, 1);
  WAITV_BAR(4)
  computeB(0);
  FENCE_BAR
  storeP(0);

  for (int kc = 1; kc < 32; ++kc) {
    if (kc < 31) {
      stageK((kc + 1) & 1, kc + 1);
      stageV((kc + 1) & 1, kc + 1);
      // in-order retirement: drain to 8 retires this tile's 4 loads (and any
      // older stores); next-tile loads + newest stores stay in flight.
      WAITV_BAR(8)
    } else {
      WAITV_BAR(4)
    }
    computeB(kc & 1);
    FENCE_BAR
    storeP(kc);
  }

  // ---- epilogue: combine kh halves via Ks scratch, write ctx ----
  float* fbuf = reinterpret_cast<float*>(&Ks[0][0][0]); // 64x64 f32 = 16 KB
  __syncthreads();
  if (kh == 1) {
#pragma unroll
    for (int reg = 0; reg < 16; ++reg) {
      int qloc = (reg & 3) + 8 * (reg >> 2) + 4 * hi;
      fbuf[(qh * 32 + qloc) * 64 + q32]      = oaccA[reg];
      fbuf[(qh * 32 + qloc) * 64 + 32 + q32] = oaccB[reg];
    }
  }
  __syncthreads();
  bf16* cs = reinterpret_cast<bf16*>(&Vs[0][0][0]); // [64][72] bf16 = 9 KB
  if (kh == 0) {
#pragma unroll
    for (int reg = 0; reg < 16; ++reg) {
      int qloc = (reg & 3) + 8 * (reg >> 2) + 4 * hi;
      cs[(qh * 32 + qloc) * 72 + q32] =
          (bf16)(oaccA[reg] + fbuf[(qh * 32 + qloc) * 64 + q32]);
      cs[(qh * 32 + qloc) * 72 + 32 + q32] =
          (bf16)(oaccB[reg] + fbuf[(qh * 32 + qloc) * 64 + 32 + q32]);
    }
  }
  __syncthreads();
  {
    int b = bh >> 4, h = bh & 15;
    int row = tid >> 2, cseg = (tid & 3) * 16;
    bf16* cp = ctx + ((size_t)b * S + qb * 64 + row) * D + h * HD + cseg;
    *reinterpret_cast<bf16x8*>(cp) =
        *reinterpret_cast<const bf16x8*>(&cs[row * 72 + cseg]);
    *reinterpret_cast<bf16x8*>(cp + 8) =
        *reinterpret_cast<const bf16x8*>(&cs[row * 72 + cseg + 8]);
  }
}

// ---------------------------------------------------------------------------
// Kernel 4: output projection. out(fp32) = ctx(bf16) @ Wo + bo.
// grid (512), block 256. XCD-chunked swizzle.
// ---------------------------------------------------------------------------
__global__ __launch_bounds__(256) void out_gemm(
    const bf16* __restrict__ ctx, const bf16* __restrict__ Wto,
    const float* __restrict__ bo, float* __restrict__ Out)
{
  int x = blockIdx.x;
  int swz = (x & 7) * 64 + (x >> 3);
  int mt = swz >> 3, nt = swz & 7;
  int m0 = mt * 128, n0 = nt * 128;
  int tid = threadIdx.x, lane = tid & 63, w = tid >> 6;
  int wm = (w >> 1) * 64, wn = (w & 1) * 64;
  int lr = lane & 15, lg = lane >> 4;

  __shared__ __align__(16) bf16 As[2][128][32];
  __shared__ __align__(16) bf16 Bs[2][128][32];

  f32x4 acc[4][4] = {};

  int srow = w * 32 + (lane >> 2);
  int scol = (lane & 3) * 8;

  auto stage = [&](int buf, int ks) {
    const bf16* ga = ctx + (size_t)(m0 + srow) * D + ks * 32 + scol;
    bf16* la = &As[buf][w * 32][0];
    gload16(ga, la);
    gload16(ga + 16 * D, la + 16 * 32);
    const bf16* gb = Wto + (size_t)(n0 + srow) * D + ks * 32 + scol;
    bf16* lb = &Bs[buf][w * 32][0];
    gload16(gb, lb);
    gload16(gb + 16 * D, lb + 16 * 32);
  };

  stage(0, 0);
  for (int ks = 0; ks < 32; ++ks) {
    __syncthreads();
    if (ks < 31) stage((ks + 1) & 1, ks + 1);
    int buf = ks & 1;
    bf16x8 af[4], bfr[4];
#pragma unroll
    for (int i = 0; i < 4; ++i)
      af[i] = *reinterpret_cast<const bf16x8*>(&As[buf][wm + i * 16 + lr][8 * lg]);
#pragma unroll
    for (int j = 0; j < 4; ++j)
      bfr[j] = *reinterpret_cast<const bf16x8*>(&Bs[buf][wn + j * 16 + lr][8 * lg]);
#pragma unroll
    for (int i = 0; i < 4; ++i)
#pragma unroll
      for (int j = 0; j < 4; ++j)
        acc[i][j] = MFMA(af[i], bfr[j], acc[i][j]);
  }

#pragma unroll
  for (int i = 0; i < 4; ++i)
#pragma unroll
    for (int j = 0; j < 4; ++j) {
      int n = n0 + wn + j * 16 + lr;
      float bias_n = bo[n];
#pragma unroll
      for (int r = 0; r < 4; ++r)
        Out[(size_t)(m0 + wm + i * 16 + 4 * lg + r) * D + n] = acc[i][j][r] + bias_n;
    }
}

// ---------------------------------------------------------------------------
extern "C" void kernel_launch(void* const* d_in, const int* in_sizes, int n_in,
                              void* d_out, int out_size, void* d_ws, size_t ws_size,
                              hipStream_t stream)
{
  const float* query = (const float*)d_in[0];
  const float* key   = (const float*)d_in[1];
  const float* value = (const float*)d_in[2];
  const float* Wq = (const float*)d_in[3]; const float* bq = (const float*)d_in[4];
  const float* Wk = (const float*)d_in[5]; const float* bk = (const float*)d_in[6];
  const float* Wv = (const float*)d_in[7]; const float* bv = (const float*)d_in[8];
  const float* Wo = (const float*)d_in[9]; const float* bo = (const float*)d_in[10];

  float* out  = (float*)d_out;
  float* attn = out + (size_t)M * D; // 8388608 floats

  char* ws = (char*)d_ws;
  const size_t MiB = 1048576;
  bf16* WtAll = (bf16*)ws;                    // 8 MiB (4 x 1024x1024)
  bf16* Xb    = (bf16*)(ws + 8 * MiB);        // 48 MiB (3 x 8192x1024)
  bf16* Qb    = (bf16*)(ws + 56 * MiB);       // 16 MiB
  bf16* Kb    = (bf16*)(ws + 72 * MiB);       // 16 MiB
  bf16* Vtb   = (bf16*)(ws + 88 * MiB);       // 16 MiB
  bf16* ctx   = Xb;                           // reuse: Xb dead after qkv_gemm

  convert_all<<<dim3(7168), 256, 0, stream>>>(query, key, value,
                                              Wq, Wk, Wv, Wo, Xb, WtAll);
  qkv_gemm<<<dim3(512, 3), 256, 0, stream>>>(Xb, WtAll, bq, bk, bv, Qb, Kb, Vtb);
  attn_kernel<<<dim3(2048), 256, 0, stream>>>(Qb, Kb, Vtb, attn, ctx);
  out_gemm<<<dim3(512), 256, 0, stream>>>(ctx, WtAll + (size_t)3 * D * D, bo, out);
}

// Round 11
// 381.571 us; speedup vs baseline: 1.5496x; 1.1537x over previous
//
#include <hip/hip_runtime.h>
#include <hip/hip_bf16.h>

typedef __bf16 bf16;
typedef __bf16 bf16x8 __attribute__((ext_vector_type(8)));
typedef __bf16 bf16x4 __attribute__((ext_vector_type(4)));
typedef __bf16 bf16x2 __attribute__((ext_vector_type(2)));
typedef float  f32x4  __attribute__((ext_vector_type(4)));
typedef float  f32x16 __attribute__((ext_vector_type(16)));
typedef unsigned int u32;

#define MFMA(A, B, C)   __builtin_amdgcn_mfma_f32_16x16x32_bf16((A), (B), (C), 0, 0, 0)
#define MFMA32(A, B, C) __builtin_amdgcn_mfma_f32_32x32x16_bf16((A), (B), (C), 0, 0, 0)

static constexpr int BATCH = 4, S = 2048, D = 1024, NH = 16, HD = 64;
static constexpr int M = BATCH * S; // 8192
static constexpr float KL = 0.045084220027780106f; // log2(e)/sqrt(1024)

__device__ __forceinline__ void gload16(const void* g, void* l) {
  __builtin_amdgcn_global_load_lds(
      (const __attribute__((address_space(1))) void*)g,
      (__attribute__((address_space(3))) void*)l, 16, 0, 0);
}

__device__ __forceinline__ float fexp2(float x) {
#if __has_builtin(__builtin_amdgcn_exp2f)
  return __builtin_amdgcn_exp2f(x);
#else
  return exp2f(x);
#endif
}

__device__ __forceinline__ u32 pack2(float a, float b) {
  union { bf16x2 h; u32 u; } c;
  c.h = (bf16x2){(bf16)a, (bf16)b};
  return c.u;
}

union U4 { u32 w[4]; bf16x8 v; };

// counted-vmcnt FENCED barrier: drain current tile's loads + ALL LDS ops,
// with a compiler memory fence so no LDS/VM op is reordered across it.
#define WAITV_BAR(n)                                                     \
  asm volatile("s_waitcnt vmcnt(" #n ") lgkmcnt(0)" ::: "memory");       \
  __builtin_amdgcn_s_barrier();                                          \
  __builtin_amdgcn_sched_barrier(0);

// plain fenced barrier (LDS producer->consumer across waves)
#define FENCE_BAR                                                        \
  asm volatile("s_waitcnt lgkmcnt(0)" ::: "memory");                     \
  __builtin_amdgcn_s_barrier();                                          \
  __builtin_amdgcn_sched_barrier(0);

// ---------------------------------------------------------------------------
// Kernel 1: fused converts.
// blocks [0, 6144): X fp32->bf16 (query/key/value -> Xb, 2048 blocks each)
// blocks [6144, 7168): W fp32->bf16 transposed (Wt[n][k] = W[k][n], 256 x 4)
// ---------------------------------------------------------------------------
__global__ __launch_bounds__(256) void convert_all(
    const float* __restrict__ X0, const float* __restrict__ X1,
    const float* __restrict__ X2,
    const float* __restrict__ W0, const float* __restrict__ W1,
    const float* __restrict__ W2, const float* __restrict__ W3,
    bf16* __restrict__ Xb, bf16* __restrict__ WtAll)
{
  int blk = blockIdx.x;
  int tid = threadIdx.x;
  if (blk < 6144) {
    int t = blk >> 11;              // tensor 0..2
    int bx = blk & 2047;
    const float* X = t == 0 ? X0 : t == 1 ? X1 : X2;
    bf16* Yp = Xb + (size_t)t * M * D;
    int idx = bx * 256 + tid;
#pragma unroll
    for (int i = 0; i < 4; ++i) {
      size_t j = (size_t)idx + (size_t)i * 524288;
      float4 v = reinterpret_cast<const float4*>(X)[j];
      bf16x4 o; o[0] = (bf16)v.x; o[1] = (bf16)v.y; o[2] = (bf16)v.z; o[3] = (bf16)v.w;
      reinterpret_cast<bf16x4*>(Yp)[j] = o;
    }
  } else {
    int wb = blk - 6144;            // 0..1023
    int wy = wb >> 8;               // weight 0..3
    int bx = wb & 255;
    const float* W = wy == 0 ? W0 : wy == 1 ? W1 : wy == 2 ? W2 : W3;
    bf16* dst = WtAll + (size_t)wy * (D * D);
    int k0 = (bx >> 4) * 64, n0 = (bx & 15) * 64;
    __shared__ __align__(16) bf16 T[64][72];
#pragma unroll
    for (int i = 0; i < 4; ++i) {
      int c = tid + i * 256, r = c >> 4, seg = c & 15;
      float4 v = *reinterpret_cast<const float4*>(W + (size_t)(k0 + r) * D + n0 + seg * 4);
      T[seg * 4 + 0][r] = (bf16)v.x; T[seg * 4 + 1][r] = (bf16)v.y;
      T[seg * 4 + 2][r] = (bf16)v.z; T[seg * 4 + 3][r] = (bf16)v.w;
    }
    __syncthreads();
#pragma unroll
    for (int i = 0; i < 2; ++i) {
      int c = tid + i * 256, r = c >> 3, seg = c & 7;
      *reinterpret_cast<bf16x8*>(dst + (size_t)(n0 + r) * D + k0 + seg * 8) =
          *reinterpret_cast<const bf16x8*>(&T[r][seg * 8]);
    }
  }
}

// ---------------------------------------------------------------------------
// Kernel 2: QKV projection GEMM. Q output pre-scaled by KL = log2e/sqrt(D).
// grid (512, 3), block 256 = 4 waves. XCD-chunked block swizzle.
// Q/K out: [bh][s][64]; V out transposed: [bh][64][s].
// ---------------------------------------------------------------------------
__global__ __launch_bounds__(256) void qkv_gemm(
    const bf16* __restrict__ Xb, const bf16* __restrict__ WtAll,
    const float* __restrict__ bq, const float* __restrict__ bk, const float* __restrict__ bv,
    bf16* __restrict__ Qb, bf16* __restrict__ Kb, bf16* __restrict__ Vtb)
{
  int v = blockIdx.y;
  const bf16*  X    = Xb + (size_t)v * M * D;
  const bf16*  Wt   = WtAll + (size_t)v * (D * D);
  const float* bias = v == 0 ? bq : v == 1 ? bk : bv;

  int x = blockIdx.x;
  int swz = (x & 7) * 64 + (x >> 3); // XCD-chunked, bijective for 512
  int mt = swz >> 3, nt = swz & 7;
  int m0 = mt * 128, n0 = nt * 128;
  int tid = threadIdx.x, lane = tid & 63, w = tid >> 6;
  int wm = (w >> 1) * 64, wn = (w & 1) * 64;
  int lr = lane & 15, lg = lane >> 4;

  __shared__ __align__(16) unsigned char smem[34816];
  auto As = reinterpret_cast<bf16(*)[128][32]>(smem);          // [2][128][32]
  auto Bs = reinterpret_cast<bf16(*)[128][32]>(smem + 16384);  // [2][128][32]

  f32x4 acc[4][4] = {};

  int srow = w * 32 + (lane >> 2);
  int scol = (lane & 3) * 8;

  auto stage = [&](int buf, int ks) {
    const bf16* ga = X + (size_t)(m0 + srow) * D + ks * 32 + scol;
    bf16* la = &As[buf][w * 32][0];
    gload16(ga, la);
    gload16(ga + 16 * D, la + 16 * 32);
    const bf16* gb = Wt + (size_t)(n0 + srow) * D + ks * 32 + scol;
    bf16* lb = &Bs[buf][w * 32][0];
    gload16(gb, lb);
    gload16(gb + 16 * D, lb + 16 * 32);
  };

  stage(0, 0);
  for (int ks = 0; ks < 32; ++ks) {
    __syncthreads();
    if (ks < 31) stage((ks + 1) & 1, ks + 1);
    int buf = ks & 1;
    bf16x8 af[4], bfr[4];
#pragma unroll
    for (int i = 0; i < 4; ++i)
      af[i] = *reinterpret_cast<const bf16x8*>(&As[buf][wm + i * 16 + lr][8 * lg]);
#pragma unroll
    for (int j = 0; j < 4; ++j)
      bfr[j] = *reinterpret_cast<const bf16x8*>(&Bs[buf][wn + j * 16 + lr][8 * lg]);
#pragma unroll
    for (int i = 0; i < 4; ++i)
#pragma unroll
      for (int j = 0; j < 4; ++j)
        acc[i][j] = MFMA(af[i], bfr[j], acc[i][j]);
  }
  __syncthreads();

  if (v < 2) { // Q/K: LDS [m][n] then coalesced store to [bh][s][64]
    bf16* Out = v == 0 ? Qb : Kb;
    float qs = v == 0 ? KL : 1.0f;
    auto Es = reinterpret_cast<bf16(*)[128]>(smem);
#pragma unroll
    for (int i = 0; i < 4; ++i)
#pragma unroll
      for (int j = 0; j < 4; ++j) {
        int n = wn + j * 16 + lr;
        float bias_n = bias[n0 + n];
#pragma unroll
        for (int r = 0; r < 4; ++r)
          Es[wm + i * 16 + 4 * lg + r][n] = (bf16)((acc[i][j][r] + bias_n) * qs);
      }
    __syncthreads();
#pragma unroll
    for (int i = 0; i < 8; ++i) {
      int c = tid + i * 256, r = c >> 4, seg = c & 15;
      int mg = m0 + r, b = mg >> 11, s = mg & 2047;
      int ng = n0 + seg * 8, h = ng >> 6, d = ng & 63;
      *reinterpret_cast<bf16x8*>(Out + (((size_t)(b * NH + h)) * S + s) * HD + d) =
          *reinterpret_cast<const bf16x8*>(&Es[r][seg * 8]);
    }
  } else { // V: LDS [n][m] (transposed) then coalesced store to [bh][64][s]
    auto Es = reinterpret_cast<bf16(*)[136]>(smem);
#pragma unroll
    for (int i = 0; i < 4; ++i)
#pragma unroll
      for (int j = 0; j < 4; ++j) {
        int n = wn + j * 16 + lr;
        float bias_n = bias[n0 + n];
        bf16x4 t;
#pragma unroll
        for (int r = 0; r < 4; ++r) t[r] = (bf16)(acc[i][j][r] + bias_n);
        *reinterpret_cast<bf16x4*>(&Es[n][wm + i * 16 + 4 * lg]) = t;
      }
    __syncthreads();
#pragma unroll
    for (int i = 0; i < 8; ++i) {
      int c = tid + i * 256, r = c >> 4, seg = c & 15;
      int ng = n0 + r, h = ng >> 6, d = ng & 63;
      int mg = m0 + seg * 8, b = mg >> 11, s = mg & 2047;
      *reinterpret_cast<bf16x8*>(Vtb + (((size_t)(b * NH + h)) * HD + d) * S + s) =
          *reinterpret_cast<const bf16x8*>(&Es[r][seg * 8]);
    }
  }
}

// ---------------------------------------------------------------------------
// Kernel 3: fused attention (R10 structure; storeP regrouped for 256B-per-
// instruction NT contiguity: 16 consecutive lanes cover one attn row).
// ---------------------------------------------------------------------------
__global__ __launch_bounds__(256) void attn_kernel(
    const bf16* __restrict__ Qb, const bf16* __restrict__ Kb, const bf16* __restrict__ Vtb,
    float* __restrict__ attn_out, bf16* __restrict__ ctx)
{
  int xx = blockIdx.x;
  int xcd = xx & 7, r8 = xx >> 3;
  int bh = xcd + 8 * (r8 >> 5);            // 8 sequential heads per XCD
  int qb = r8 & 31;
  int tid = threadIdx.x, lane = tid & 63, w = tid >> 6;
  int q32 = lane & 31, hi = lane >> 5;
  int qh = w & 1, kh = w >> 1;

  __shared__ __align__(16) bf16 Ks[2][64][64];
  __shared__ __align__(16) bf16 Vs[2][64][64];
  __shared__ __align__(16) float Ps[64][68];   // P tile f32, padded stride
  __shared__ float sums[2][64];

  int q_row = qb * 64 + qh * 32 + q32;
  const bf16* Qrow = Qb + ((size_t)bh * S + q_row) * HD;
  bf16x8 qreg[4];
#pragma unroll
  for (int c = 0; c < 4; ++c)
    qreg[c] = *reinterpret_cast<const bf16x8*>(Qrow + c * 16 + 8 * hi);

  auto stageK = [&](int buf, int kc) {
    const bf16* base = Kb + ((size_t)bh * S + kc * 64) * HD;
#pragma unroll
    for (int i = 0; i < 2; ++i) {
      int c = i * 256 + tid, row = c >> 3, j = c & 7;
      gload16(base + row * HD + 8 * (j ^ (row & 7)),
              reinterpret_cast<bf16*>(&Ks[buf][0][0]) + c * 8);
    }
  };
  auto stageV = [&](int buf, int kc) {
    const bf16* base = Vtb + (size_t)bh * HD * S + kc * 64;
#pragma unroll
    for (int i = 0; i < 2; ++i) {
      int c = i * 256 + tid, row = c >> 3, j = c & 7;
      gload16(base + (size_t)row * S + 8 * (j ^ (row & 7)),
              reinterpret_cast<bf16*>(&Vs[buf][0][0]) + c * 8);
    }
  };

  int krow = kh * 32 + q32, ks7 = krow & 7;

  // ---- pass A: row sum of exp2(s) over this wave's key-half ----
  float xs[4] = {0.f, 0.f, 0.f, 0.f};
  stageK(0, 0);
  for (int kc = 0; kc < 32; ++kc) {
    if (kc < 31) {
      stageK((kc + 1) & 1, kc + 1);
      WAITV_BAR(2)
    } else {
      WAITV_BAR(0)
    }
    int buf = kc & 1;
    f32x16 sa = {};
#pragma unroll
    for (int c = 0; c < 4; ++c) {
      bf16x8 kf = *reinterpret_cast<const bf16x8*>(&Ks[buf][krow][8 * ((2 * c + hi) ^ ks7)]);
      sa = MFMA32(kf, qreg[c], sa);
    }
#pragma unroll
    for (int r = 0; r < 16; ++r) xs[r & 3] += fexp2(sa[r]);
    FENCE_BAR
  }
  float lrun = (xs[0] + xs[1]) + (xs[2] + xs[3]);
  lrun += __shfl_xor(lrun, 32);            // combine hi pair (same q)
  if (hi == 0) sums[kh][qh * 32 + q32] = lrun;
  __syncthreads();
  float lg2l = __log2f(sums[0][qh * 32 + q32] + sums[1][qh * 32 + q32]);

  // ---- pass B: recompute, P -> LDS, PV accumulate; coalesced NT store ----
  f32x16 oaccA = {}, oaccB = {};           // d-halves 0,1 (named: rule #20)
  float* ablk = attn_out + ((size_t)bh * S + qb * 64) * S;

  auto computeB = [&](int buf) {
    f32x16 sa = {};
#pragma unroll
    for (int c = 0; c < 4; ++c) {
      bf16x8 kf = *reinterpret_cast<const bf16x8*>(&Ks[buf][krow][8 * ((2 * c + hi) ^ ks7)]);
      sa = MFMA32(kf, qreg[c], sa);
    }
    u32 pku[8];
#pragma unroll
    for (int rq = 0; rq < 4; ++rq) {
      f32x4 pv;
#pragma unroll
      for (int j = 0; j < 4; ++j) pv[j] = fexp2(sa[rq * 4 + j] - lg2l);
      *reinterpret_cast<f32x4*>(&Ps[qh * 32 + q32][kh * 32 + 8 * rq + 4 * hi]) = pv;
      pku[rq * 2 + 0] = pack2(pv[0], pv[1]);
      pku[rq * 2 + 1] = pack2(pv[2], pv[3]);
    }
#pragma unroll
    for (int c2 = 0; c2 < 2; ++c2) {
      u32 myw0 = hi ? pku[4 * c2 + 2] : pku[4 * c2 + 0];
      u32 myw1 = hi ? pku[4 * c2 + 3] : pku[4 * c2 + 1];
      u32 sdw0 = hi ? pku[4 * c2 + 0] : pku[4 * c2 + 2];
      u32 sdw1 = hi ? pku[4 * c2 + 1] : pku[4 * c2 + 3];
      u32 r0 = __shfl_xor(sdw0, 32);
      u32 r1 = __shfl_xor(sdw1, 32);
      U4 f;
      f.w[0] = hi ? r0 : myw0;
      f.w[1] = hi ? r1 : myw1;
      f.w[2] = hi ? myw0 : r0;
      f.w[3] = hi ? myw1 : r1;
      {
        int vrow = q32, vs7 = vrow & 7;      // d-half 0
        bf16x8 vf = *reinterpret_cast<const bf16x8*>(
            &Vs[buf][vrow][8 * ((4 * kh + 2 * c2 + hi) ^ vs7)]);
        oaccA = MFMA32(f.v, vf, oaccA);
      }
      {
        int vrow = 32 + q32, vs7 = vrow & 7; // d-half 1
        bf16x8 vf = *reinterpret_cast<const bf16x8*>(
            &Vs[buf][vrow][8 * ((4 * kh + 2 * c2 + hi) ^ vs7)]);
        oaccB = MFMA32(f.v, vf, oaccB);
      }
    }
  };

  // coalesced NT attn store: 16 consecutive lanes cover ONE row -> each wave
  // instruction writes 4 segments of 256B (full per-tile row), vs 16x64B
  // before. NT packets are 4x more contiguous.
  int r16 = tid >> 4, c16 = (tid & 15) * 4;
  auto storeP = [&](int kc) {
#pragma unroll
    for (int s = 0; s < 4; ++s) {
      int row = s * 16 + r16;
      __builtin_nontemporal_store(
          *reinterpret_cast<const f32x4*>(&Ps[row][c16]),
          reinterpret_cast<f32x4*>(ablk + (size_t)row * S + kc * 64 + c16));
    }
  };

  // prologue + peeled iter 0 (no stores in flight yet)
  stageK(0, 0); stageV(0, 0);
  stageK(1, 1); stageV(1, 1);
  WAITV_BAR(4)
  computeB(0);
  FENCE_BAR
  storeP(0);

  for (int kc = 1; kc < 32; ++kc) {
    if (kc < 31) {
      stageK((kc + 1) & 1, kc + 1);
      stageV((kc + 1) & 1, kc + 1);
      // in-order retirement: drain to 8 retires this tile's 4 loads (and any
      // older stores); next-tile loads + newest stores stay in flight.
      WAITV_BAR(8)
    } else {
      WAITV_BAR(4)
    }
    computeB(kc & 1);
    FENCE_BAR
    storeP(kc);
  }

  // ---- epilogue: combine kh halves via Ks scratch, write ctx ----
  float* fbuf = reinterpret_cast<float*>(&Ks[0][0][0]); // 64x64 f32 = 16 KB
  __syncthreads();
  if (kh == 1) {
#pragma unroll
    for (int reg = 0; reg < 16; ++reg) {
      int qloc = (reg & 3) + 8 * (reg >> 2) + 4 * hi;
      fbuf[(qh * 32 + qloc) * 64 + q32]      = oaccA[reg];
      fbuf[(qh * 32 + qloc) * 64 + 32 + q32] = oaccB[reg];
    }
  }
  __syncthreads();
  bf16* cs = reinterpret_cast<bf16*>(&Vs[0][0][0]); // [64][72] bf16 = 9 KB
  if (kh == 0) {
#pragma unroll
    for (int reg = 0; reg < 16; ++reg) {
      int qloc = (reg & 3) + 8 * (reg >> 2) + 4 * hi;
      cs[(qh * 32 + qloc) * 72 + q32] =
          (bf16)(oaccA[reg] + fbuf[(qh * 32 + qloc) * 64 + q32]);
      cs[(qh * 32 + qloc) * 72 + 32 + q32] =
          (bf16)(oaccB[reg] + fbuf[(qh * 32 + qloc) * 64 + 32 + q32]);
    }
  }
  __syncthreads();
  {
    int b = bh >> 4, h = bh & 15;
    int row = tid >> 2, cseg = (tid & 3) * 16;
    bf16* cp = ctx + ((size_t)b * S + qb * 64 + row) * D + h * HD + cseg;
    *reinterpret_cast<bf16x8*>(cp) =
        *reinterpret_cast<const bf16x8*>(&cs[row * 72 + cseg]);
    *reinterpret_cast<bf16x8*>(cp + 8) =
        *reinterpret_cast<const bf16x8*>(&cs[row * 72 + cseg + 8]);
  }
}

// ---------------------------------------------------------------------------
// Kernel 4: output projection. out(fp32) = ctx(bf16) @ Wo + bo.
// grid (512), block 256. XCD-chunked swizzle.
// ---------------------------------------------------------------------------
__global__ __launch_bounds__(256) void out_gemm(
    const bf16* __restrict__ ctx, const bf16* __restrict__ Wto,
    const float* __restrict__ bo, float* __restrict__ Out)
{
  int x = blockIdx.x;
  int swz = (x & 7) * 64 + (x >> 3);
  int mt = swz >> 3, nt = swz & 7;
  int m0 = mt * 128, n0 = nt * 128;
  int tid = threadIdx.x, lane = tid & 63, w = tid >> 6;
  int wm = (w >> 1) * 64, wn = (w & 1) * 64;
  int lr = lane & 15, lg = lane >> 4;

  __shared__ __align__(16) bf16 As[2][128][32];
  __shared__ __align__(16) bf16 Bs[2][128][32];

  f32x4 acc[4][4] = {};

  int srow = w * 32 + (lane >> 2);
  int scol = (lane & 3) * 8;

  auto stage = [&](int buf, int ks) {
    const bf16* ga = ctx + (size_t)(m0 + srow) * D + ks * 32 + scol;
    bf16* la = &As[buf][w * 32][0];
    gload16(ga, la);
    gload16(ga + 16 * D, la + 16 * 32);
    const bf16* gb = Wto + (size_t)(n0 + srow) * D + ks * 32 + scol;
    bf16* lb = &Bs[buf][w * 32][0];
    gload16(gb, lb);
    gload16(gb + 16 * D, lb + 16 * 32);
  };

  stage(0, 0);
  for (int ks = 0; ks < 32; ++ks) {
    __syncthreads();
    if (ks < 31) stage((ks + 1) & 1, ks + 1);
    int buf = ks & 1;
    bf16x8 af[4], bfr[4];
#pragma unroll
    for (int i = 0; i < 4; ++i)
      af[i] = *reinterpret_cast<const bf16x8*>(&As[buf][wm + i * 16 + lr][8 * lg]);
#pragma unroll
    for (int j = 0; j < 4; ++j)
      bfr[j] = *reinterpret_cast<const bf16x8*>(&Bs[buf][wn + j * 16 + lr][8 * lg]);
#pragma unroll
    for (int i = 0; i < 4; ++i)
#pragma unroll
      for (int j = 0; j < 4; ++j)
        acc[i][j] = MFMA(af[i], bfr[j], acc[i][j]);
  }

#pragma unroll
  for (int i = 0; i < 4; ++i)
#pragma unroll
    for (int j = 0; j < 4; ++j) {
      int n = n0 + wn + j * 16 + lr;
      float bias_n = bo[n];
#pragma unroll
      for (int r = 0; r < 4; ++r)
        Out[(size_t)(m0 + wm + i * 16 + 4 * lg + r) * D + n] = acc[i][j][r] + bias_n;
    }
}

// ---------------------------------------------------------------------------
extern "C" void kernel_launch(void* const* d_in, const int* in_sizes, int n_in,
                              void* d_out, int out_size, void* d_ws, size_t ws_size,
                              hipStream_t stream)
{
  const float* query = (const float*)d_in[0];
  const float* key   = (const float*)d_in[1];
  const float* value = (const float*)d_in[2];
  const float* Wq = (const float*)d_in[3]; const float* bq = (const float*)d_in[4];
  const float* Wk = (const float*)d_in[5]; const float* bk = (const float*)d_in[6];
  const float* Wv = (const float*)d_in[7]; const float* bv = (const float*)d_in[8];
  const float* Wo = (const float*)d_in[9]; const float* bo = (const float*)d_in[10];

  float* out  = (float*)d_out;
  float* attn = out + (size_t)M * D; // 8388608 floats

  char* ws = (char*)d_ws;
  const size_t MiB = 1048576;
  bf16* WtAll = (bf16*)ws;                    // 8 MiB (4 x 1024x1024)
  bf16* Xb    = (bf16*)(ws + 8 * MiB);        // 48 MiB (3 x 8192x1024)
  bf16* Qb    = (bf16*)(ws + 56 * MiB);       // 16 MiB
  bf16* Kb    = (bf16*)(ws + 72 * MiB);       // 16 MiB
  bf16* Vtb   = (bf16*)(ws + 88 * MiB);       // 16 MiB
  bf16* ctx   = Xb;                           // reuse: Xb dead after qkv_gemm

  convert_all<<<dim3(7168), 256, 0, stream>>>(query, key, value,
                                              Wq, Wk, Wv, Wo, Xb, WtAll);
  qkv_gemm<<<dim3(512, 3), 256, 0, stream>>>(Xb, WtAll, bq, bk, bv, Qb, Kb, Vtb);
  attn_kernel<<<dim3(2048), 256, 0, stream>>>(Qb, Kb, Vtb, attn, ctx);
  out_gemm<<<dim3(512), 256, 0, stream>>>(ctx, WtAll + (size_t)3 * D * D, bo, out);
}

// Round 13
// 376.169 us; speedup vs baseline: 1.5719x; 1.0144x over previous
//
#include <hip/hip_runtime.h>
#include <hip/hip_bf16.h>

typedef __bf16 bf16;
typedef __bf16 bf16x8 __attribute__((ext_vector_type(8)));
typedef __bf16 bf16x4 __attribute__((ext_vector_type(4)));
typedef __bf16 bf16x2 __attribute__((ext_vector_type(2)));
typedef float  f32x4  __attribute__((ext_vector_type(4)));
typedef float  f32x16 __attribute__((ext_vector_type(16)));
typedef unsigned int u32;

#define MFMA(A, B, C)   __builtin_amdgcn_mfma_f32_16x16x32_bf16((A), (B), (C), 0, 0, 0)
#define MFMA32(A, B, C) __builtin_amdgcn_mfma_f32_32x32x16_bf16((A), (B), (C), 0, 0, 0)

static constexpr int BATCH = 4, S = 2048, D = 1024, NH = 16, HD = 64;
static constexpr int M = BATCH * S; // 8192
static constexpr float KL = 0.045084220027780106f; // log2(e)/sqrt(1024)

__device__ __forceinline__ void gload16(const void* g, void* l) {
  __builtin_amdgcn_global_load_lds(
      (const __attribute__((address_space(1))) void*)g,
      (__attribute__((address_space(3))) void*)l, 16, 0, 0);
}

__device__ __forceinline__ float fexp2(float x) {
#if __has_builtin(__builtin_amdgcn_exp2f)
  return __builtin_amdgcn_exp2f(x);
#else
  return exp2f(x);
#endif
}

__device__ __forceinline__ u32 pack2(float a, float b) {
  union { bf16x2 h; u32 u; } c;
  c.h = (bf16x2){(bf16)a, (bf16)b};
  return c.u;
}

union U4 { u32 w[4]; bf16x8 v; };

// counted-vmcnt FENCED barrier: drain current tile's loads + ALL LDS ops,
// with a compiler memory fence so no LDS/VM op is reordered across it.
#define WAITV_BAR(n)                                                     \
  asm volatile("s_waitcnt vmcnt(" #n ") lgkmcnt(0)" ::: "memory");       \
  __builtin_amdgcn_s_barrier();                                          \
  __builtin_amdgcn_sched_barrier(0);

// plain fenced barrier (LDS producer->consumer across waves)
#define FENCE_BAR                                                        \
  asm volatile("s_waitcnt lgkmcnt(0)" ::: "memory");                     \
  __builtin_amdgcn_s_barrier();                                          \
  __builtin_amdgcn_sched_barrier(0);

// ---------------------------------------------------------------------------
// Kernel 1: fused converts.
// blocks [0, 6144): X fp32->bf16 (query/key/value -> Xb, 2048 blocks each)
// blocks [6144, 7168): W fp32->bf16 transposed (Wt[n][k] = W[k][n], 256 x 4)
// ---------------------------------------------------------------------------
__global__ __launch_bounds__(256) void convert_all(
    const float* __restrict__ X0, const float* __restrict__ X1,
    const float* __restrict__ X2,
    const float* __restrict__ W0, const float* __restrict__ W1,
    const float* __restrict__ W2, const float* __restrict__ W3,
    bf16* __restrict__ Xb, bf16* __restrict__ WtAll)
{
  int blk = blockIdx.x;
  int tid = threadIdx.x;
  if (blk < 6144) {
    int t = blk >> 11;              // tensor 0..2
    int bx = blk & 2047;
    const float* X = t == 0 ? X0 : t == 1 ? X1 : X2;
    bf16* Yp = Xb + (size_t)t * M * D;
    int idx = bx * 256 + tid;
#pragma unroll
    for (int i = 0; i < 4; ++i) {
      size_t j = (size_t)idx + (size_t)i * 524288;
      float4 v = reinterpret_cast<const float4*>(X)[j];
      bf16x4 o; o[0] = (bf16)v.x; o[1] = (bf16)v.y; o[2] = (bf16)v.z; o[3] = (bf16)v.w;
      reinterpret_cast<bf16x4*>(Yp)[j] = o;
    }
  } else {
    int wb = blk - 6144;            // 0..1023
    int wy = wb >> 8;               // weight 0..3
    int bx = wb & 255;
    const float* W = wy == 0 ? W0 : wy == 1 ? W1 : wy == 2 ? W2 : W3;
    bf16* dst = WtAll + (size_t)wy * (D * D);
    int k0 = (bx >> 4) * 64, n0 = (bx & 15) * 64;
    __shared__ __align__(16) bf16 T[64][72];
#pragma unroll
    for (int i = 0; i < 4; ++i) {
      int c = tid + i * 256, r = c >> 4, seg = c & 15;
      float4 v = *reinterpret_cast<const float4*>(W + (size_t)(k0 + r) * D + n0 + seg * 4);
      T[seg * 4 + 0][r] = (bf16)v.x; T[seg * 4 + 1][r] = (bf16)v.y;
      T[seg * 4 + 2][r] = (bf16)v.z; T[seg * 4 + 3][r] = (bf16)v.w;
    }
    __syncthreads();
#pragma unroll
    for (int i = 0; i < 2; ++i) {
      int c = tid + i * 256, r = c >> 3, seg = c & 7;
      *reinterpret_cast<bf16x8*>(dst + (size_t)(n0 + r) * D + k0 + seg * 8) =
          *reinterpret_cast<const bf16x8*>(&T[r][seg * 8]);
    }
  }
}

// ---------------------------------------------------------------------------
// Kernel 2: QKV projection GEMM. Q output pre-scaled by KL = log2e/sqrt(D).
// grid (512, 3), block 256 = 4 waves. XCD-chunked block swizzle.
// Q/K out: [bh][s][64]; V out transposed: [bh][64][s].
// ---------------------------------------------------------------------------
__global__ __launch_bounds__(256) void qkv_gemm(
    const bf16* __restrict__ Xb, const bf16* __restrict__ WtAll,
    const float* __restrict__ bq, const float* __restrict__ bk, const float* __restrict__ bv,
    bf16* __restrict__ Qb, bf16* __restrict__ Kb, bf16* __restrict__ Vtb)
{
  int v = blockIdx.y;
  const bf16*  X    = Xb + (size_t)v * M * D;
  const bf16*  Wt   = WtAll + (size_t)v * (D * D);
  const float* bias = v == 0 ? bq : v == 1 ? bk : bv;

  int x = blockIdx.x;
  int swz = (x & 7) * 64 + (x >> 3); // XCD-chunked, bijective for 512
  int mt = swz >> 3, nt = swz & 7;
  int m0 = mt * 128, n0 = nt * 128;
  int tid = threadIdx.x, lane = tid & 63, w = tid >> 6;
  int wm = (w >> 1) * 64, wn = (w & 1) * 64;
  int lr = lane & 15, lg = lane >> 4;

  __shared__ __align__(16) unsigned char smem[34816];
  auto As = reinterpret_cast<bf16(*)[128][32]>(smem);          // [2][128][32]
  auto Bs = reinterpret_cast<bf16(*)[128][32]>(smem + 16384);  // [2][128][32]

  f32x4 acc[4][4] = {};

  int srow = w * 32 + (lane >> 2);
  int scol = (lane & 3) * 8;

  auto stage = [&](int buf, int ks) {
    const bf16* ga = X + (size_t)(m0 + srow) * D + ks * 32 + scol;
    bf16* la = &As[buf][w * 32][0];
    gload16(ga, la);
    gload16(ga + 16 * D, la + 16 * 32);
    const bf16* gb = Wt + (size_t)(n0 + srow) * D + ks * 32 + scol;
    bf16* lb = &Bs[buf][w * 32][0];
    gload16(gb, lb);
    gload16(gb + 16 * D, lb + 16 * 32);
  };

  stage(0, 0);
  for (int ks = 0; ks < 32; ++ks) {
    __syncthreads();
    if (ks < 31) stage((ks + 1) & 1, ks + 1);
    int buf = ks & 1;
    bf16x8 af[4], bfr[4];
#pragma unroll
    for (int i = 0; i < 4; ++i)
      af[i] = *reinterpret_cast<const bf16x8*>(&As[buf][wm + i * 16 + lr][8 * lg]);
#pragma unroll
    for (int j = 0; j < 4; ++j)
      bfr[j] = *reinterpret_cast<const bf16x8*>(&Bs[buf][wn + j * 16 + lr][8 * lg]);
#pragma unroll
    for (int i = 0; i < 4; ++i)
#pragma unroll
      for (int j = 0; j < 4; ++j)
        acc[i][j] = MFMA(af[i], bfr[j], acc[i][j]);
  }
  __syncthreads();

  if (v < 2) { // Q/K: LDS [m][n] then coalesced store to [bh][s][64]
    bf16* Out = v == 0 ? Qb : Kb;
    float qs = v == 0 ? KL : 1.0f;
    auto Es = reinterpret_cast<bf16(*)[128]>(smem);
#pragma unroll
    for (int i = 0; i < 4; ++i)
#pragma unroll
      for (int j = 0; j < 4; ++j) {
        int n = wn + j * 16 + lr;
        float bias_n = bias[n0 + n];
#pragma unroll
        for (int r = 0; r < 4; ++r)
          Es[wm + i * 16 + 4 * lg + r][n] = (bf16)((acc[i][j][r] + bias_n) * qs);
      }
    __syncthreads();
#pragma unroll
    for (int i = 0; i < 8; ++i) {
      int c = tid + i * 256, r = c >> 4, seg = c & 15;
      int mg = m0 + r, b = mg >> 11, s = mg & 2047;
      int ng = n0 + seg * 8, h = ng >> 6, d = ng & 63;
      *reinterpret_cast<bf16x8*>(Out + (((size_t)(b * NH + h)) * S + s) * HD + d) =
          *reinterpret_cast<const bf16x8*>(&Es[r][seg * 8]);
    }
  } else { // V: LDS [n][m] (transposed) then coalesced store to [bh][64][s]
    auto Es = reinterpret_cast<bf16(*)[136]>(smem);
#pragma unroll
    for (int i = 0; i < 4; ++i)
#pragma unroll
      for (int j = 0; j < 4; ++j) {
        int n = wn + j * 16 + lr;
        float bias_n = bias[n0 + n];
        bf16x4 t;
#pragma unroll
        for (int r = 0; r < 4; ++r) t[r] = (bf16)(acc[i][j][r] + bias_n);
        *reinterpret_cast<bf16x4*>(&Es[n][wm + i * 16 + 4 * lg]) = t;
      }
    __syncthreads();
#pragma unroll
    for (int i = 0; i < 8; ++i) {
      int c = tid + i * 256, r = c >> 4, seg = c & 15;
      int ng = n0 + r, h = ng >> 6, d = ng & 63;
      int mg = m0 + seg * 8, b = mg >> 11, s = mg & 2047;
      *reinterpret_cast<bf16x8*>(Vtb + (((size_t)(b * NH + h)) * HD + d) * S + s) =
          *reinterpret_cast<const bf16x8*>(&Es[r][seg * 8]);
    }
  }
}

// ---------------------------------------------------------------------------
// Kernel 3: fused attention, 8 waves / 128 q-rows per block (512 threads).
// Waves: qh = w&3 (q-quarter of 32 rows), kh = w>>2 (key-half).
// K/V tile staged ONCE per 128 q-rows (1 gload16/thread each).
// Epilogue combines kh halves via Ps (fbuf) and writes ctx in TWO 64-row
// halves through Vs as [64][72] (fits: 9216B <= 16384B; R12's bug was a
// single [128][72] buffer overflowing Vs into Ps).
// ---------------------------------------------------------------------------
__global__ __launch_bounds__(512, 4) void attn_kernel(
    const bf16* __restrict__ Qb, const bf16* __restrict__ Kb, const bf16* __restrict__ Vtb,
    float* __restrict__ attn_out, bf16* __restrict__ ctx)
{
  int xx = blockIdx.x;                     // 1024 blocks
  int xcd = xx & 7, r8 = xx >> 3;          // r8 in [0,128)
  int bh = xcd + 8 * (r8 >> 4);            // 8 sequential heads per XCD
  int qp = r8 & 15;                        // q-tile of 128 rows
  int tid = threadIdx.x, lane = tid & 63, w = tid >> 6;
  int q32 = lane & 31, hi = lane >> 5;
  int qh = w & 3, kh = w >> 2;

  __shared__ __align__(16) bf16 Ks[2][64][64];
  __shared__ __align__(16) bf16 Vs[2][64][64];
  __shared__ __align__(16) float Ps[128][68];  // P tile f32 / epilogue fbuf
  __shared__ float sums[2][128];

  int q_row = qp * 128 + qh * 32 + q32;
  const bf16* Qrow = Qb + ((size_t)bh * S + q_row) * HD;
  bf16x8 qreg[4];
#pragma unroll
  for (int c = 0; c < 4; ++c)
    qreg[c] = *reinterpret_cast<const bf16x8*>(Qrow + c * 16 + 8 * hi);

  // stage 64x64 bf16 tile: 512 threads -> exactly 1 gload16 each.
  auto stageK = [&](int buf, int kc) {
    const bf16* base = Kb + ((size_t)bh * S + kc * 64) * HD;
    int row = tid >> 3, j = tid & 7;
    gload16(base + row * HD + 8 * (j ^ (row & 7)),
            reinterpret_cast<bf16*>(&Ks[buf][0][0]) + tid * 8);
  };
  auto stageV = [&](int buf, int kc) {
    const bf16* base = Vtb + (size_t)bh * HD * S + kc * 64;
    int row = tid >> 3, j = tid & 7;
    gload16(base + (size_t)row * S + 8 * (j ^ (row & 7)),
            reinterpret_cast<bf16*>(&Vs[buf][0][0]) + tid * 8);
  };

  int krow = kh * 32 + q32, ks7 = krow & 7;

  // ---- pass A: row sum of exp2(s) over this wave's key-half ----
  float xs[4] = {0.f, 0.f, 0.f, 0.f};
  stageK(0, 0);
  for (int kc = 0; kc < 32; ++kc) {
    if (kc < 31) {
      stageK((kc + 1) & 1, kc + 1);
      WAITV_BAR(1)
    } else {
      WAITV_BAR(0)
    }
    int buf = kc & 1;
    f32x16 sa = {};
#pragma unroll
    for (int c = 0; c < 4; ++c) {
      bf16x8 kf = *reinterpret_cast<const bf16x8*>(&Ks[buf][krow][8 * ((2 * c + hi) ^ ks7)]);
      sa = MFMA32(kf, qreg[c], sa);
    }
#pragma unroll
    for (int r = 0; r < 16; ++r) xs[r & 3] += fexp2(sa[r]);
    FENCE_BAR
  }
  float lrun = (xs[0] + xs[1]) + (xs[2] + xs[3]);
  lrun += __shfl_xor(lrun, 32);            // combine hi pair (same q)
  if (hi == 0) sums[kh][qh * 32 + q32] = lrun;
  __syncthreads();
  float lg2l = __log2f(sums[0][qh * 32 + q32] + sums[1][qh * 32 + q32]);

  // ---- pass B: recompute, P -> LDS, PV accumulate; coalesced NT store ----
  f32x16 oaccA = {}, oaccB = {};           // d-halves 0,1 (named: rule #20)
  float* ablk = attn_out + ((size_t)bh * S + qp * 128) * S;

  auto computeB = [&](int buf) {
    f32x16 sa = {};
#pragma unroll
    for (int c = 0; c < 4; ++c) {
      bf16x8 kf = *reinterpret_cast<const bf16x8*>(&Ks[buf][krow][8 * ((2 * c + hi) ^ ks7)]);
      sa = MFMA32(kf, qreg[c], sa);
    }
    u32 pku[8];
#pragma unroll
    for (int rq = 0; rq < 4; ++rq) {
      f32x4 pv;
#pragma unroll
      for (int j = 0; j < 4; ++j) pv[j] = fexp2(sa[rq * 4 + j] - lg2l);
      *reinterpret_cast<f32x4*>(&Ps[qh * 32 + q32][kh * 32 + 8 * rq + 4 * hi]) = pv;
      pku[rq * 2 + 0] = pack2(pv[0], pv[1]);
      pku[rq * 2 + 1] = pack2(pv[2], pv[3]);
    }
#pragma unroll
    for (int c2 = 0; c2 < 2; ++c2) {
      u32 myw0 = hi ? pku[4 * c2 + 2] : pku[4 * c2 + 0];
      u32 myw1 = hi ? pku[4 * c2 + 3] : pku[4 * c2 + 1];
      u32 sdw0 = hi ? pku[4 * c2 + 0] : pku[4 * c2 + 2];
      u32 sdw1 = hi ? pku[4 * c2 + 1] : pku[4 * c2 + 3];
      u32 r0 = __shfl_xor(sdw0, 32);
      u32 r1 = __shfl_xor(sdw1, 32);
      U4 f;
      f.w[0] = hi ? r0 : myw0;
      f.w[1] = hi ? r1 : myw1;
      f.w[2] = hi ? myw0 : r0;
      f.w[3] = hi ? myw1 : r1;
      {
        int vrow = q32, vs7 = vrow & 7;      // d-half 0
        bf16x8 vf = *reinterpret_cast<const bf16x8*>(
            &Vs[buf][vrow][8 * ((4 * kh + 2 * c2 + hi) ^ vs7)]);
        oaccA = MFMA32(f.v, vf, oaccA);
      }
      {
        int vrow = 32 + q32, vs7 = vrow & 7; // d-half 1
        bf16x8 vf = *reinterpret_cast<const bf16x8*>(
            &Vs[buf][vrow][8 * ((4 * kh + 2 * c2 + hi) ^ vs7)]);
        oaccB = MFMA32(f.v, vf, oaccB);
      }
    }
  };

  // coalesced NT attn store: 16 consecutive lanes cover ONE row -> each wave
  // instruction writes 4 segments of 256B. 512 threads cover 128 rows.
  int r16 = tid >> 4, c16 = (tid & 15) * 4;
  auto storeP = [&](int kc) {
#pragma unroll
    for (int s = 0; s < 4; ++s) {
      int row = s * 32 + r16;
      __builtin_nontemporal_store(
          *reinterpret_cast<const f32x4*>(&Ps[row][c16]),
          reinterpret_cast<f32x4*>(ablk + (size_t)row * S + kc * 64 + c16));
    }
  };

  // prologue + peeled iter 0 (no stores in flight yet)
  stageK(0, 0); stageV(0, 0);
  stageK(1, 1); stageV(1, 1);
  WAITV_BAR(2)
  computeB(0);
  FENCE_BAR
  storeP(0);

  for (int kc = 1; kc < 32; ++kc) {
    if (kc < 31) {
      stageK((kc + 1) & 1, kc + 1);
      stageV((kc + 1) & 1, kc + 1);
      // queue: loads(kc)[2], stores(kc-1)[4], loads(kc+1)[2] = 8;
      // vmcnt(6) drains the 2 oldest = tile-kc loads (in-order retirement).
      WAITV_BAR(6)
    } else {
      // queue: loads(31)[2] + stores(30)[4]; drain the loads.
      WAITV_BAR(4)
    }
    computeB(kc & 1);
    FENCE_BAR
    storeP(kc);
  }

  // ---- epilogue: combine kh halves via Ps (fbuf), write ctx in 2 halves ----
  float* fbuf = &Ps[0][0];                 // flat, stride 64 (128x64 f32)
  __syncthreads();                         // all storeP(31) Ps reads done
  if (kh == 1) {
#pragma unroll
    for (int reg = 0; reg < 16; ++reg) {
      int qloc = (reg & 3) + 8 * (reg >> 2) + 4 * hi;
      fbuf[(qh * 32 + qloc) * 64 + q32]      = oaccA[reg];
      fbuf[(qh * 32 + qloc) * 64 + 32 + q32] = oaccB[reg];
    }
  }
  __syncthreads();
  bf16* cs = reinterpret_cast<bf16*>(&Vs[0][0][0]); // [64][72] bf16 = 9216B
  int b = bh >> 4, h = bh & 15;
#pragma unroll
  for (int half = 0; half < 2; ++half) {
    if (kh == 0 && (qh >> 1) == half) {
      int qr32 = (qh & 1) * 32;            // row base within this half
#pragma unroll
      for (int reg = 0; reg < 16; ++reg) {
        int qloc = (reg & 3) + 8 * (reg >> 2) + 4 * hi;
        int gq = qh * 32 + qloc;           // global q-row in [0,128)
        cs[(qr32 + qloc) * 72 + q32] =
            (bf16)(oaccA[reg] + fbuf[gq * 64 + q32]);
        cs[(qr32 + qloc) * 72 + 32 + q32] =
            (bf16)(oaccB[reg] + fbuf[gq * 64 + 32 + q32]);
      }
    }
    __syncthreads();
    {
      int row = tid >> 3, cseg = (tid & 7) * 8; // 8 threads cover one row
      bf16* cp = ctx + ((size_t)b * S + qp * 128 + half * 64 + row) * D
                 + h * HD + cseg;
      *reinterpret_cast<bf16x8*>(cp) =
          *reinterpret_cast<const bf16x8*>(&cs[row * 72 + cseg]);
    }
    __syncthreads();                       // cs reads done before next half
  }
}

// ---------------------------------------------------------------------------
// Kernel 4: output projection. out(fp32) = ctx(bf16) @ Wo + bo.
// grid (512), block 256. XCD-chunked swizzle.
// ---------------------------------------------------------------------------
__global__ __launch_bounds__(256) void out_gemm(
    const bf16* __restrict__ ctx, const bf16* __restrict__ Wto,
    const float* __restrict__ bo, float* __restrict__ Out)
{
  int x = blockIdx.x;
  int swz = (x & 7) * 64 + (x >> 3);
  int mt = swz >> 3, nt = swz & 7;
  int m0 = mt * 128, n0 = nt * 128;
  int tid = threadIdx.x, lane = tid & 63, w = tid >> 6;
  int wm = (w >> 1) * 64, wn = (w & 1) * 64;
  int lr = lane & 15, lg = lane >> 4;

  __shared__ __align__(16) bf16 As[2][128][32];
  __shared__ __align__(16) bf16 Bs[2][128][32];

  f32x4 acc[4][4] = {};

  int srow = w * 32 + (lane >> 2);
  int scol = (lane & 3) * 8;

  auto stage = [&](int buf, int ks) {
    const bf16* ga = ctx + (size_t)(m0 + srow) * D + ks * 32 + scol;
    bf16* la = &As[buf][w * 32][0];
    gload16(ga, la);
    gload16(ga + 16 * D, la + 16 * 32);
    const bf16* gb = Wto + (size_t)(n0 + srow) * D + ks * 32 + scol;
    bf16* lb = &Bs[buf][w * 32][0];
    gload16(gb, lb);
    gload16(gb + 16 * D, lb + 16 * 32);
  };

  stage(0, 0);
  for (int ks = 0; ks < 32; ++ks) {
    __syncthreads();
    if (ks < 31) stage((ks + 1) & 1, ks + 1);
    int buf = ks & 1;
    bf16x8 af[4], bfr[4];
#pragma unroll
    for (int i = 0; i < 4; ++i)
      af[i] = *reinterpret_cast<const bf16x8*>(&As[buf][wm + i * 16 + lr][8 * lg]);
#pragma unroll
    for (int j = 0; j < 4; ++j)
      bfr[j] = *reinterpret_cast<const bf16x8*>(&Bs[buf][wn + j * 16 + lr][8 * lg]);
#pragma unroll
    for (int i = 0; i < 4; ++i)
#pragma unroll
      for (int j = 0; j < 4; ++j)
        acc[i][j] = MFMA(af[i], bfr[j], acc[i][j]);
  }

#pragma unroll
  for (int i = 0; i < 4; ++i)
#pragma unroll
    for (int j = 0; j < 4; ++j) {
      int n = n0 + wn + j * 16 + lr;
      float bias_n = bo[n];
#pragma unroll
      for (int r = 0; r < 4; ++r)
        Out[(size_t)(m0 + wm + i * 16 + 4 * lg + r) * D + n] = acc[i][j][r] + bias_n;
    }
}

// ---------------------------------------------------------------------------
extern "C" void kernel_launch(void* const* d_in, const int* in_sizes, int n_in,
                              void* d_out, int out_size, void* d_ws, size_t ws_size,
                              hipStream_t stream)
{
  const float* query = (const float*)d_in[0];
  const float* key   = (const float*)d_in[1];
  const float* value = (const float*)d_in[2];
  const float* Wq = (const float*)d_in[3]; const float* bq = (const float*)d_in[4];
  const float* Wk = (const float*)d_in[5]; const float* bk = (const float*)d_in[6];
  const float* Wv = (const float*)d_in[7]; const float* bv = (const float*)d_in[8];
  const float* Wo = (const float*)d_in[9]; const float* bo = (const float*)d_in[10];

  float* out  = (float*)d_out;
  float* attn = out + (size_t)M * D; // 8388608 floats

  char* ws = (char*)d_ws;
  const size_t MiB = 1048576;
  bf16* WtAll = (bf16*)ws;                    // 8 MiB (4 x 1024x1024)
  bf16* Xb    = (bf16*)(ws + 8 * MiB);        // 48 MiB (3 x 8192x1024)
  bf16* Qb    = (bf16*)(ws + 56 * MiB);       // 16 MiB
  bf16* Kb    = (bf16*)(ws + 72 * MiB);       // 16 MiB
  bf16* Vtb   = (bf16*)(ws + 88 * MiB);       // 16 MiB
  bf16* ctx   = Xb;                           // reuse: Xb dead after qkv_gemm

  convert_all<<<dim3(7168), 256, 0, stream>>>(query, key, value,
                                              Wq, Wk, Wv, Wo, Xb, WtAll);
  qkv_gemm<<<dim3(512, 3), 256, 0, stream>>>(Xb, WtAll, bq, bk, bv, Qb, Kb, Vtb);
  attn_kernel<<<dim3(1024), 512, 0, stream>>>(Qb, Kb, Vtb, attn, ctx);
  out_gemm<<<dim3(512), 256, 0, stream>>>(ctx, WtAll + (size_t)3 * D * D, bo, out);
}